// Round 14
// baseline (563.317 us; speedup 1.0000x reference)
//
#include <hip/hip_runtime.h>

using bf16x8 = __attribute__((ext_vector_type(8))) __bf16;
using bf16x4 = __attribute__((ext_vector_type(4))) __bf16;
using f32x4  = __attribute__((ext_vector_type(4))) float;

#define MN    150000
#define NEDGE 300000
#define NG    6000
#define NSCAN 586   // ceil(MN/256)

// ---------------- dual-dtype helpers ----------------
// flags[0]=1 -> float tensors are fp32 (else bf16)
// flags[1]=1 -> edge_index is int64 (else int32)
// flags[2]=1 -> batch is int64 (else int32)
__device__ __forceinline__ float loadF(const void* p, size_t i, int f32) {
    return f32 ? ((const float*)p)[i] : (float)((const __bf16*)p)[i];
}
__device__ __forceinline__ int loadI(const int* p, size_t i, int i64) {
    return i64 ? p[2 * i] : p[i];
}

// ---------------- dtype probe ----------------
__global__ void k_probe(const void* W1a, const int* ei, const int* batch, int* flags) {
    __shared__ int s_f32, s_einz, s_bnz;
    if (threadIdx.x == 0) { s_f32 = 0; s_einz = 0; s_bnz = 0; }
    __syncthreads();
    const unsigned short* w = (const unsigned short*)W1a;
    for (int i = threadIdx.x; i < 1792; i += 256) {
        int e = (w[i] >> 7) & 0xFF;
        if (e >= 0xF0) s_f32 = 1;   // impossible for genuine |w|<=0.38 bf16
    }
    for (int i = threadIdx.x; i < 2048; i += 256)
        if (ei[2 * i + 1] != 0) s_einz = 1;
    for (int i = threadIdx.x; i < 2048; i += 256)
        if (batch[75000 + 2 * i + 1] != 0) s_bnz = 1;
    __syncthreads();
    if (threadIdx.x == 0) {
        flags[0] = s_f32;
        flags[1] = s_einz ? 0 : 1;
        flags[2] = s_bnz ? 0 : 1;
    }
}

// all 7 weight transposes in one launch: Wt[j][n][k] = W[j][k][n]
__global__ void k_cvtWT(const void* W0, const void* W1, const void* W2, const void* W3,
                        const void* W4, const void* W5, const void* W6,
                        __bf16* __restrict__ Wt, const int* __restrict__ flags) {
    int j = blockIdx.x >> 8;
    int n = blockIdx.x & 255, k = threadIdx.x;
    const void* Ws[7] = {W0, W1, W2, W3, W4, W5, W6};
    Wt[(size_t)j * 65536 + (size_t)n * 256 + k] = (__bf16)loadF(Ws[j], (size_t)k * 256 + n, flags[0]);
}

// ---------------- CSR build (by dst) ----------------
__global__ void k_deg(const int* __restrict__ ei, int* __restrict__ cnt, int* __restrict__ total,
                      int nE, const int* __restrict__ flags) {
    int e = blockIdx.x * 256 + threadIdx.x;
    if (blockIdx.x == 0 && threadIdx.x == 0) *total = 0;   // no reader until k_alloc
    if (e >= nE) return;
    int i64 = flags[1];
    int d = loadI(ei, (size_t)nE + e, i64);
    if ((unsigned)d >= (unsigned)MN) d = 0;
    atomicAdd(&cnt[d], 1);
}

// contiguous region allocation (replaces 3-kernel prefix scan): node order of regions
// is irrelevant -- k_fill/staging only need elist[offs[v]..offs[v]+deg) contiguous.
// Per-wave inclusive scan + ONE atomic per wave (2344 total).
__global__ void k_alloc(const int* __restrict__ cnt, int* __restrict__ offs,
                        int* __restrict__ total, int n) {
    int v = blockIdx.x * 256 + threadIdx.x;
    int lane = threadIdx.x & 63;
    int d = (v < n) ? cnt[v] : 0;
    int x = d;
#pragma unroll
    for (int o = 1; o < 64; o <<= 1) {
        int y = __shfl_up(x, o, 64);
        if (lane >= o) x += y;
    }
    int wsum = __shfl(x, 63, 64);
    int base = 0;
    if (lane == 63) base = atomicAdd(total, wsum);
    base = __shfl(base, 63, 64);
    if (v < n) offs[v] = base + x - d;   // exclusive within wave + wave base
}

__global__ void k_fill(const int* __restrict__ ei, const int* __restrict__ offs,
                       int* __restrict__ cur, int* __restrict__ elist, int nE,
                       const int* __restrict__ flags) {
    int e = blockIdx.x * 256 + threadIdx.x;
    if (e >= nE) return;
    int i64 = flags[1];
    int s = loadI(ei, (size_t)e, i64);
    int d = loadI(ei, (size_t)nE + e, i64);
    if ((unsigned)s >= (unsigned)MN) s = 0;
    if ((unsigned)d >= (unsigned)MN) d = 0;
    int pos = offs[d] + atomicAdd(&cur[d], 1);
    // guard vs rocprof-replay corrupting stateful atomics (timed runs rebuild cleanly)
    if ((unsigned)pos < (unsigned)NEDGE) elist[pos] = s;
}

// ---------------- MFMA GEMM core, 128-row tile, CI x MI accumulator ----------------
// CI = 16-col groups per wave, MI = 16-row groups (128 rows -> MI=8). r3-proven body.
template<int CI, int MI>
__device__ __forceinline__ void gemm_core(const __bf16* lA, const __bf16* __restrict__ WT,
                                          int n0, int lm, int lq, f32x4 acc[CI][MI]) {
    const __bf16* wp = WT + (size_t)(n0 + lm) * 256 + lq * 8;
    bf16x8 wf[CI], wn[CI];
#pragma unroll
    for (int ci = 0; ci < CI; ++ci)
        wf[ci] = *(const bf16x8*)(wp + ci * 16 * 256);
#pragma unroll
    for (int kt = 0; kt < 8; ++kt) {
        if (kt < 7) {
#pragma unroll
            for (int ci = 0; ci < CI; ++ci)
                wn[ci] = *(const bf16x8*)(wp + ci * 16 * 256 + (kt + 1) * 32);
        }
        int sw = (((kt * 4 + lq) ^ (lm & 7)) << 3);
        bf16x8 xf[MI];
#pragma unroll
        for (int mi = 0; mi < MI; ++mi)
            xf[mi] = *(const bf16x8*)(lA + (mi * 16 + lm) * 256 + sw);
#pragma unroll
        for (int ci = 0; ci < CI; ++ci)
#pragma unroll
            for (int mi = 0; mi < MI; ++mi)
                acc[ci][mi] = __builtin_amdgcn_mfma_f32_16x16x32_bf16(
                    wf[ci], xf[mi], acc[ci][mi], 0, 0, 0);
#pragma unroll
        for (int ci = 0; ci < CI; ++ci) wf[ci] = wn[ci];
    }
}

// epilogue helper: write acc tile (relu(acc+bias)) into swizzled LDS
template<int CI, int MI>
__device__ __forceinline__ void epi_to_lds(__bf16* lA, f32x4 acc[CI][MI], const void* bias,
                                           int n0, int lm, int lq, int f32) {
#pragma unroll
    for (int ci = 0; ci < CI; ++ci) {
        int n4 = n0 + ci * 16 + lq * 4;
        float b0 = loadF(bias, n4 + 0, f32), b1 = loadF(bias, n4 + 1, f32);
        float b2 = loadF(bias, n4 + 2, f32), b3 = loadF(bias, n4 + 3, f32);
#pragma unroll
        for (int mi = 0; mi < MI; ++mi) {
            int m = mi * 16 + lm;
            f32x4 a = acc[ci][mi];
            bf16x4 v;
            v[0] = (__bf16)fmaxf(a[0] + b0, 0.f);
            v[1] = (__bf16)fmaxf(a[1] + b1, 0.f);
            v[2] = (__bf16)fmaxf(a[2] + b2, 0.f);
            v[3] = (__bf16)fmaxf(a[3] + b3, 0.f);
            *(bf16x4*)(lA + m * 256 + (((n4 >> 3) ^ (m & 7)) << 3) + (n4 & 7)) = v;
        }
    }
}

// epilogue helper: full-line stores from swizzled LDS to Y; RW = rows per wave
template<int RW>
__device__ __forceinline__ void lds_to_global(const __bf16* lA, __bf16* __restrict__ Y,
                                              int bm, int w, int lane, int M_) {
    int half = lane >> 5;
    int cc = lane & 31;
#pragma unroll
    for (int it = 0; it < RW / 2; ++it) {
        int r = w * RW + it * 2 + half;
        int gm = bm + r;
        if (gm < M_) {
            bf16x8 v = *(const bf16x8*)(lA + r * 256 + ((cc ^ (r & 7)) << 3));
            *(bf16x8*)(Y + (size_t)gm * 256 + cc * 8) = v;
        }
    }
}

// ---------------- fused staging: lA[r] = H[bm+r] + sum_{dst(e)=bm+r} H[src(e)] ----------------
// 512 threads: 8 threads/row, fp32 accumulation in 32 regs, 2 passes over 128 rows.
// This sits in a narrow feasibility pocket (session-verified): fewer lanes/row doubles
// HBM fetch (r10); more passes serializes (r4); bigger register batching spills (r7/r11);
// gll-DMA and dense tables regress (r8/r6). Do not perturb without new evidence.
__device__ __forceinline__ void stage128_agg512(const __bf16* __restrict__ H, __bf16* lA,
                                                const int* __restrict__ offs,
                                                const int* __restrict__ deg,
                                                const int* __restrict__ elist,
                                                int bm, int t, int M_) {
    int tc = t & 7;            // col-group: bf16 cols tc*32 .. tc*32+31
    int rl = t >> 3;           // row within pass (0..63)
#pragma unroll 1
    for (int p = 0; p < 2; ++p) {
        int r = p * 64 + rl;
        int gr = bm + r;
        if (gr >= M_) gr = M_ - 1;
        const __bf16* self = H + (size_t)gr * 256 + tc * 32;
        float acc[32];
        {
            bf16x8 v0 = *(const bf16x8*)(self + 0);
            bf16x8 v1 = *(const bf16x8*)(self + 8);
            bf16x8 v2 = *(const bf16x8*)(self + 16);
            bf16x8 v3 = *(const bf16x8*)(self + 24);
#pragma unroll
            for (int j = 0; j < 8; ++j) {
                acc[j]      = (float)v0[j];
                acc[8 + j]  = (float)v1[j];
                acc[16 + j] = (float)v2[j];
                acc[24 + j] = (float)v3[j];
            }
        }
        int b = offs[gr], d = min(deg[gr], 1024);
        int e = 0;
        for (; e + 1 < d; e += 2) {
            int u0 = elist[b + e];
            int u1 = elist[b + e + 1];
            if ((unsigned)u0 >= (unsigned)MN) u0 = 0;
            if ((unsigned)u1 >= (unsigned)MN) u1 = 0;
            const __bf16* nb0 = H + (size_t)u0 * 256 + tc * 32;
            const __bf16* nb1 = H + (size_t)u1 * 256 + tc * 32;
            bf16x8 a0 = *(const bf16x8*)(nb0 + 0);
            bf16x8 a1 = *(const bf16x8*)(nb0 + 8);
            bf16x8 a2 = *(const bf16x8*)(nb0 + 16);
            bf16x8 a3 = *(const bf16x8*)(nb0 + 24);
            bf16x8 c0 = *(const bf16x8*)(nb1 + 0);
            bf16x8 c1 = *(const bf16x8*)(nb1 + 8);
            bf16x8 c2 = *(const bf16x8*)(nb1 + 16);
            bf16x8 c3 = *(const bf16x8*)(nb1 + 24);
#pragma unroll
            for (int j = 0; j < 8; ++j) {
                acc[j]      += (float)a0[j] + (float)c0[j];
                acc[8 + j]  += (float)a1[j] + (float)c1[j];
                acc[16 + j] += (float)a2[j] + (float)c2[j];
                acc[24 + j] += (float)a3[j] + (float)c3[j];
            }
        }
        if (e < d) {
            int u = elist[b + e];
            if ((unsigned)u >= (unsigned)MN) u = 0;
            const __bf16* nb = H + (size_t)u * 256 + tc * 32;
            bf16x8 n0 = *(const bf16x8*)(nb + 0);
            bf16x8 n1 = *(const bf16x8*)(nb + 8);
            bf16x8 n2 = *(const bf16x8*)(nb + 16);
            bf16x8 n3 = *(const bf16x8*)(nb + 24);
#pragma unroll
            for (int j = 0; j < 8; ++j) {
                acc[j]      += (float)n0[j];
                acc[8 + j]  += (float)n1[j];
                acc[16 + j] += (float)n2[j];
                acc[24 + j] += (float)n3[j];
            }
        }
#pragma unroll
        for (int q = 0; q < 4; ++q) {
            int c = tc * 4 + q;      // bf16x8-chunk index 0..31
            bf16x8 o;
#pragma unroll
            for (int j = 0; j < 8; ++j) o[j] = (__bf16)acc[q * 8 + j];
            *(bf16x8*)(lA + r * 256 + ((c ^ (r & 7)) << 3)) = o;
        }
    }
}

// ---------------- fused GIN layer: Y = relu( relu((H+agg)@Wa+ba) @ Wb + bb ) ----------------
// r3/r9-proven config: 128-row tile, 8 waves, ci=2, 2 blocks/CU. 117.6us/layer floor.
// do_pool: last layer skips the Y write and segment-sums the tile into POOL (batch sorted).
__global__ __launch_bounds__(512, 4) void k_agg_mlp(
    const __bf16* __restrict__ H, const int* __restrict__ offs, const int* __restrict__ deg,
    const int* __restrict__ elist,
    const __bf16* __restrict__ WaT, const void* __restrict__ ba,
    const __bf16* __restrict__ WbT, const void* __restrict__ bb,
    __bf16* __restrict__ Y, const int* __restrict__ batch,
    float* __restrict__ pool, float* __restrict__ cntf, int do_pool,
    int M_, const int* __restrict__ flags) {
    __shared__ __align__(16) __bf16 lA[128 * 256];
    __shared__ int sbatch[128];
    int t = threadIdx.x;
    int f32 = flags[0];
    int bm = blockIdx.x * 128;
    int w = t >> 6, lane = t & 63, lm = lane & 15, lq = lane >> 4;
    int n0 = w * 32;

    stage128_agg512(H, lA, offs, deg, elist, bm, t, M_);
    if (do_pool && t < 128) {
        int gm = bm + t;
        sbatch[t] = (gm < M_) ? loadI(batch, gm, flags[2]) : -1;
    }
    __syncthreads();

    {
        f32x4 acc[2][8] = {};
        gemm_core<2, 8>(lA, WaT, n0, lm, lq, acc);
        __syncthreads();   // all lA reads done; safe to overwrite with mid
        epi_to_lds<2, 8>(lA, acc, ba, n0, lm, lq, f32);
    }
    __syncthreads();

    f32x4 acc2[2][8] = {};
    gemm_core<2, 8>(lA, WbT, n0, lm, lq, acc2);
    __syncthreads();       // all lA reads done; safe to overwrite with result
    epi_to_lds<2, 8>(lA, acc2, bb, n0, lm, lq, f32);
    __syncthreads();

    if (!do_pool) {
        lds_to_global<16>(lA, Y, bm, w, lane, M_);
    } else {
        // segment mean-pool straight from LDS: thread = (col, row-half)
        int c = t & 255;
        int h2 = t >> 8;
        int g = -1;
        float acc = 0.f, run = 0.f;
        int rbeg = h2 * 64;
        for (int r = rbeg; r < rbeg + 64; ++r) {
            int bg = sbatch[r];
            if (bg < 0) break;   // past M_ (batch sorted)
            if ((unsigned)bg >= (unsigned)NG) bg = 0;
            float v = (float)lA[r * 256 + (((c >> 3) ^ (r & 7)) << 3) + (c & 7)];
            if (bg != g) {
                if (g >= 0) {
                    atomicAdd(&pool[(size_t)g * 256 + c], acc);
                    if (c == 0) atomicAdd(&cntf[g], run);
                }
                g = bg; acc = 0.f; run = 0.f;
            }
            acc += v; run += 1.f;
        }
        if (g >= 0) {
            atomicAdd(&pool[(size_t)g * 256 + c], acc);
            if (c == 0) atomicAdd(&cntf[g], run);
        }
    }
}

// ---------------- layer-1 GEMM with fused 7-wide gather (k_l1lite absorbed) ----------------
// Staging computes agg7 on the fly (x row + neighbor rows, fp32, same accumulation order
// as the old k_l1lite -> numerically identical) then the 7->256 linear; AGG7 buffer gone.
// 512 threads, 4 threads/row staging (r13-proven), 8-wave ci=2 GEMM path.
__global__ __launch_bounds__(512, 4) void k_gemm1(
    const void* __restrict__ x, const int* __restrict__ offs, const int* __restrict__ deg,
    const int* __restrict__ elist,
    const void* __restrict__ W1a, const void* __restrict__ b1a,
    const __bf16* __restrict__ WT, const void* __restrict__ bias,
    __bf16* __restrict__ Y, int M_, const int* __restrict__ flags) {
    __shared__ __align__(16) __bf16 lA[128 * 256];
    __shared__ float sW[7 * 256];
    __shared__ float sB[256];
    int t = threadIdx.x;
    int f32 = flags[0];
    int bm = blockIdx.x * 128;
    int w = t >> 6, lane = t & 63, lm = lane & 15, lq = lane >> 4;
    int n0 = w * 32;

    if (t < 256) sB[t] = loadF(b1a, t, f32);
    for (int i = t; i < 7 * 256; i += 512) sW[i] = loadF(W1a, i, f32);
    __syncthreads();

    {
        int r = t >> 2;                  // 4 threads/row over 128 rows
        int gr = bm + r;
        if (gr >= M_) gr = M_ - 1;
        float a[7];
#pragma unroll
        for (int k = 0; k < 7; ++k) a[k] = loadF(x, (size_t)gr * 7 + k, f32);
        int b = offs[gr], d = min(deg[gr], 1024);
        for (int e = 0; e < d; ++e) {
            int u = elist[b + e];
            if ((unsigned)u >= (unsigned)MN) u = 0;
#pragma unroll
            for (int k = 0; k < 7; ++k) a[k] += loadF(x, (size_t)u * 7 + k, f32);
        }
        int c0 = (t & 3) * 64;
#pragma unroll
        for (int s8 = 0; s8 < 8; ++s8) {
            bf16x8 o;
#pragma unroll
            for (int j = 0; j < 8; ++j) {
                int cc = c0 + s8 * 8 + j;
                float v = sB[cc];
#pragma unroll
                for (int k = 0; k < 7; ++k) v = fmaf(a[k], sW[k * 256 + cc], v);
                o[j] = (__bf16)fmaxf(v, 0.f);
            }
            int ch = (c0 >> 3) + s8;
            *(bf16x8*)(lA + r * 256 + ((ch ^ (r & 7)) << 3)) = o;
        }
    }
    __syncthreads();

    f32x4 acc[2][8] = {};
    gemm_core<2, 8>(lA, WT, n0, lm, lq, acc);
    __syncthreads();
    epi_to_lds<2, 8>(lA, acc, bias, n0, lm, lq, f32);
    __syncthreads();
    lds_to_global<16>(lA, Y, bm, w, lane, M_);
}

// ---------------- head, split-K (r9-proven): out[g] = relu(mean @ Wh1 + bh1) @ Wh2 + bh2 ----
// Per-graph block (6000-block TLP; r5 showed LDS-residency kills it); K=256 chain split
// across 4 thread-groups (chain 256 -> 64), partials reduced through LDS. Wh1 L2-served.
__global__ __launch_bounds__(512) void k_head(
    const float* __restrict__ pool, const float* __restrict__ cnt,
    const void* __restrict__ Wh1, const void* __restrict__ bh1,
    const void* __restrict__ Wh2, const void* __restrict__ bh2,
    void* __restrict__ outv, const int* __restrict__ flags) {
    int g = blockIdx.x, t = threadIdx.x;   // 512 threads
    int f32 = flags[0];
    __shared__ float p[256];
    __shared__ float hidp[4][128];
    __shared__ float hid[128];
    float inv = 1.0f / fmaxf(cnt[g], 1.0f);
    if (t < 256) p[t] = pool[(size_t)g * 256 + t] * inv;
    __syncthreads();
    {
        int n = t & 127, kh = t >> 7;      // kh in 0..3: K-chunk of 64
        int kb = kh * 64;
        float s = 0.f;
#pragma unroll 8
        for (int k = 0; k < 64; ++k)
            s = fmaf(p[kb + k], loadF(Wh1, (size_t)(kb + k) * 128 + n, f32), s);
        hidp[kh][n] = s;
    }
    __syncthreads();
    if (t < 128)
        hid[t] = fmaxf(hidp[0][t] + hidp[1][t] + hidp[2][t] + hidp[3][t]
                       + loadF(bh1, t, f32), 0.f);
    __syncthreads();
    if (t < 192) {
        int n3 = t >> 6, lane = t & 63;
        float o = hid[lane] * loadF(Wh2, (size_t)lane * 3 + n3, f32);
        o = fmaf(hid[lane + 64], loadF(Wh2, (size_t)(lane + 64) * 3 + n3, f32), o);
#pragma unroll
        for (int off = 32; off > 0; off >>= 1) o += __shfl_down(o, off, 64);
        if (lane == 0) {
            o += loadF(bh2, n3, f32);
            if (f32) ((float*)outv)[(size_t)g * 3 + n3] = o;
            else     ((__bf16*)outv)[(size_t)g * 3 + n3] = (__bf16)o;
        }
    }
}

// ---------------- launch ----------------
extern "C" void kernel_launch(void* const* d_in, const int* in_sizes, int n_in,
                              void* d_out, int out_size, void* d_ws, size_t ws_size,
                              hipStream_t stream) {
    const void* x     = d_in[0];
    const int*  ei    = (const int*)d_in[1];
    const int*  batch = (const int*)d_in[2];
    const void *W[4][2], *b[4][2];
    for (int l = 0; l < 4; ++l) {
        W[l][0] = d_in[3 + 4 * l];
        b[l][0] = d_in[4 + 4 * l];
        W[l][1] = d_in[5 + 4 * l];
        b[l][1] = d_in[6 + 4 * l];
    }
    const void* Wh1 = d_in[19];
    const void* bh1 = d_in[20];
    const void* Wh2 = d_in[21];
    const void* bh2 = d_in[22];

    char* p = (char*)d_ws;
    auto alloc = [&](size_t bytes) -> char* {
        char* r = p;
        p += (bytes + 255) & ~(size_t)255;
        return r;
    };
    __bf16* B1    = (__bf16*)alloc((size_t)MN * 256 * 2);   // 76.8 MB
    __bf16* B2    = (__bf16*)alloc((size_t)MN * 256 * 2);   // 76.8 MB
    __bf16* WT    = (__bf16*)alloc((size_t)7 * 256 * 256 * 2);
    int*    offs  = (int*)alloc((size_t)MN * 4);
    int*    cnt   = (int*)alloc((size_t)MN * 4);
    int*    elist = (int*)alloc((size_t)NEDGE * 4);
    int*    TOTAL = (int*)alloc(64);
    float*  POOL  = (float*)alloc((size_t)NG * 256 * 4);    // CNTF contiguous after
    float*  CNTF  = (float*)alloc((size_t)NG * 4);
    int*    flags = (int*)alloc(64);

    // ---- dtype probe ----
    k_probe<<<1, 256, 0, stream>>>(W[0][0], ei, batch, flags);

    // ---- transposed bf16 weights [n][k]: W1b, W2a, W2b, W3a, W3b, W4a, W4b ----
    k_cvtWT<<<7 * 256, 256, 0, stream>>>(W[0][1], W[1][0], W[1][1], W[2][0], W[2][1],
                                         W[3][0], W[3][1], WT, flags);

    // ---- CSR build (by dst): deg -> wave-scan atomic region alloc -> fill ----
    hipMemsetAsync(cnt, 0, (size_t)MN * 4, stream);
    k_deg<<<(NEDGE + 255) / 256, 256, 0, stream>>>(ei, cnt, TOTAL, NEDGE, flags);
    k_alloc<<<NSCAN, 256, 0, stream>>>(cnt, offs, TOTAL, MN);
    hipMemsetAsync(cnt, 0, (size_t)MN * 4, stream);   // cursor
    k_fill<<<(NEDGE + 255) / 256, 256, 0, stream>>>(ei, offs, cnt, elist, NEDGE, flags);
    // after k_fill, cnt[v] == degree(v)

    // ---- zero pool accumulators (POOL + CNTF contiguous) ----
    hipMemsetAsync(POOL, 0, (size_t)NG * 256 * 4 + (size_t)NG * 4, stream);

    int gblocks = (MN + 127) / 128;

    // ---- layer 1: gather-7 fused into gemm1 staging (k_l1lite + AGG7 eliminated) ----
    k_gemm1<<<gblocks, 512, 0, stream>>>(x, offs, cnt, elist,
                                         W[0][0], b[0][0], WT /*W1b^T*/, b[0][1],
                                         B1, MN, flags);

    // ---- layers 2..4: fused agg+MLP, ping-pong B1/B2; last layer pools in-epilogue ----
    __bf16* bin = B1;
    __bf16* bout = B2;
    for (int l = 1; l < 4; ++l) {
        const __bf16* WaT = WT + (size_t)(1 + 2 * (l - 1)) * 65536;
        const __bf16* WbT = WT + (size_t)(2 + 2 * (l - 1)) * 65536;
        int dp = (l == 3) ? 1 : 0;
        k_agg_mlp<<<gblocks, 512, 0, stream>>>(bin, offs, cnt, elist,
                                               WaT, b[l][0], WbT, b[l][1], bout,
                                               batch, POOL, CNTF, dp, MN, flags);
        __bf16* tmp = bin; bin = bout; bout = tmp;
    }

    // ---- split-K head ----
    k_head<<<NG, 512, 0, stream>>>(POOL, CNTF, Wh1, bh1, Wh2, bh2, d_out, flags);
}

// Round 15
// 544.186 us; speedup vs baseline: 1.0352x; 1.0352x over previous
//
#include <hip/hip_runtime.h>

using bf16x8 = __attribute__((ext_vector_type(8))) __bf16;
using bf16x4 = __attribute__((ext_vector_type(4))) __bf16;
using f32x4  = __attribute__((ext_vector_type(4))) float;

#define MN    150000
#define NEDGE 300000
#define NG    6000
#define NSCAN 586   // ceil(MN/256)

// ---------------- dual-dtype helpers ----------------
// flags[0]=1 -> float tensors are fp32 (else bf16)
// flags[1]=1 -> edge_index is int64 (else int32)
// flags[2]=1 -> batch is int64 (else int32)
__device__ __forceinline__ float loadF(const void* p, size_t i, int f32) {
    return f32 ? ((const float*)p)[i] : (float)((const __bf16*)p)[i];
}
__device__ __forceinline__ int loadI(const int* p, size_t i, int i64) {
    return i64 ? p[2 * i] : p[i];
}

// ---------------- dtype probe ----------------
__global__ void k_probe(const void* W1a, const int* ei, const int* batch, int* flags) {
    __shared__ int s_f32, s_einz, s_bnz;
    if (threadIdx.x == 0) { s_f32 = 0; s_einz = 0; s_bnz = 0; }
    __syncthreads();
    const unsigned short* w = (const unsigned short*)W1a;
    for (int i = threadIdx.x; i < 1792; i += 256) {
        int e = (w[i] >> 7) & 0xFF;
        if (e >= 0xF0) s_f32 = 1;   // impossible for genuine |w|<=0.38 bf16
    }
    for (int i = threadIdx.x; i < 2048; i += 256)
        if (ei[2 * i + 1] != 0) s_einz = 1;
    for (int i = threadIdx.x; i < 2048; i += 256)
        if (batch[75000 + 2 * i + 1] != 0) s_bnz = 1;
    __syncthreads();
    if (threadIdx.x == 0) {
        flags[0] = s_f32;
        flags[1] = s_einz ? 0 : 1;
        flags[2] = s_bnz ? 0 : 1;
    }
}

// all 7 weight transposes in one launch: Wt[j][n][k] = W[j][k][n]
__global__ void k_cvtWT(const void* W0, const void* W1, const void* W2, const void* W3,
                        const void* W4, const void* W5, const void* W6,
                        __bf16* __restrict__ Wt, const int* __restrict__ flags) {
    int j = blockIdx.x >> 8;
    int n = blockIdx.x & 255, k = threadIdx.x;
    const void* Ws[7] = {W0, W1, W2, W3, W4, W5, W6};
    Wt[(size_t)j * 65536 + (size_t)n * 256 + k] = (__bf16)loadF(Ws[j], (size_t)k * 256 + n, flags[0]);
}

// ---------------- CSR build (by dst) ----------------
__global__ void k_deg(const int* __restrict__ ei, int* __restrict__ cnt, int nE,
                      const int* __restrict__ flags) {
    int e = blockIdx.x * 256 + threadIdx.x;
    if (e >= nE) return;
    int i64 = flags[1];
    int d = loadI(ei, (size_t)nE + e, i64);
    if ((unsigned)d >= (unsigned)MN) d = 0;
    atomicAdd(&cnt[d], 1);
}
__global__ void k_blksum(const int* __restrict__ cnt, int* __restrict__ bsum, int n) {
    __shared__ int s[256];
    int t = threadIdx.x;
    int i = blockIdx.x * 256 + t;
    s[t] = (i < n) ? cnt[i] : 0;
    __syncthreads();
    for (int o = 128; o > 0; o >>= 1) {
        if (t < o) s[t] += s[t + o];
        __syncthreads();
    }
    if (t == 0) bsum[blockIdx.x] = s[0];
}
// parallel block-base scan: 1024 threads, Hillis-Steele over NSCAN elements
__global__ __launch_bounds__(1024) void k_scanb(const int* __restrict__ bsum,
                                                int* __restrict__ bbase, int nb) {
    __shared__ int s[1024];
    int t = threadIdx.x;
    int v = (t < nb) ? bsum[t] : 0;
    s[t] = v;
    __syncthreads();
#pragma unroll
    for (int o = 1; o < 1024; o <<= 1) {
        int x = (t >= o) ? s[t - o] : 0;
        __syncthreads();
        s[t] += x;
        __syncthreads();
    }
    if (t < nb) bbase[t] = s[t] - v;   // exclusive
}
__global__ void k_blkscan(const int* __restrict__ cnt, const int* __restrict__ bbase,
                          int* __restrict__ offs, int n) {
    __shared__ int s[256];
    int t = threadIdx.x;
    int i = blockIdx.x * 256 + t;
    int v = (i < n) ? cnt[i] : 0;
    s[t] = v;
    __syncthreads();
    for (int o = 1; o < 256; o <<= 1) {
        int x = (t >= o) ? s[t - o] : 0;
        __syncthreads();
        s[t] += x;
        __syncthreads();
    }
    if (i < n) offs[i] = bbase[blockIdx.x] + s[t] - v;
}
__global__ void k_fill(const int* __restrict__ ei, const int* __restrict__ offs,
                       int* __restrict__ cur, int* __restrict__ elist, int nE,
                       const int* __restrict__ flags) {
    int e = blockIdx.x * 256 + threadIdx.x;
    if (e >= nE) return;
    int i64 = flags[1];
    int s = loadI(ei, (size_t)e, i64);
    int d = loadI(ei, (size_t)nE + e, i64);
    if ((unsigned)s >= (unsigned)MN) s = 0;
    if ((unsigned)d >= (unsigned)MN) d = 0;
    int pos = offs[d] + atomicAdd(&cur[d], 1);
    // guard vs rocprof-replay corrupting stateful atomics (timed runs rebuild cleanly)
    if ((unsigned)pos < (unsigned)NEDGE) elist[pos] = s;
}

// ---------------- layer 1 lite: agg7 only -> AGG7 (fp32, padded to 8) ----------------
// 8 threads/row, one float per neighbor per thread (fully parallel across j) --
// fusing this into k_gemm1's 4-thread/row staging was 4x-redundant and regressed (r14).
__global__ __launch_bounds__(256) void k_l1lite(
    const void* __restrict__ x, const int* __restrict__ offs,
    const int* __restrict__ deg, const int* __restrict__ elist,
    float* __restrict__ agg7, const int* __restrict__ flags, int M_) {
    int f32 = flags[0];
    int t = threadIdx.x;
    int v = blockIdx.x * 32 + (t >> 3);
    int j = t & 7;
    if (v >= M_ || j >= 7) return;
    float s = loadF(x, (size_t)v * 7 + j, f32);
    int b = offs[v], d = min(deg[v], 1024);
    for (int e = 0; e < d; ++e) {
        int u = elist[b + e];
        if ((unsigned)u >= (unsigned)MN) u = 0;
        s += loadF(x, (size_t)u * 7 + j, f32);
    }
    agg7[(size_t)v * 8 + j] = s;
}

// ---------------- MFMA GEMM core, 128-row tile, CI x MI accumulator ----------------
// CI = 16-col groups per wave, MI = 16-row groups (128 rows -> MI=8). r3-proven body.
template<int CI, int MI>
__device__ __forceinline__ void gemm_core(const __bf16* lA, const __bf16* __restrict__ WT,
                                          int n0, int lm, int lq, f32x4 acc[CI][MI]) {
    const __bf16* wp = WT + (size_t)(n0 + lm) * 256 + lq * 8;
    bf16x8 wf[CI], wn[CI];
#pragma unroll
    for (int ci = 0; ci < CI; ++ci)
        wf[ci] = *(const bf16x8*)(wp + ci * 16 * 256);
#pragma unroll
    for (int kt = 0; kt < 8; ++kt) {
        if (kt < 7) {
#pragma unroll
            for (int ci = 0; ci < CI; ++ci)
                wn[ci] = *(const bf16x8*)(wp + ci * 16 * 256 + (kt + 1) * 32);
        }
        int sw = (((kt * 4 + lq) ^ (lm & 7)) << 3);
        bf16x8 xf[MI];
#pragma unroll
        for (int mi = 0; mi < MI; ++mi)
            xf[mi] = *(const bf16x8*)(lA + (mi * 16 + lm) * 256 + sw);
#pragma unroll
        for (int ci = 0; ci < CI; ++ci)
#pragma unroll
            for (int mi = 0; mi < MI; ++mi)
                acc[ci][mi] = __builtin_amdgcn_mfma_f32_16x16x32_bf16(
                    wf[ci], xf[mi], acc[ci][mi], 0, 0, 0);
#pragma unroll
        for (int ci = 0; ci < CI; ++ci) wf[ci] = wn[ci];
    }
}

// epilogue helper: write acc tile (relu(acc+bias)) into swizzled LDS
template<int CI, int MI>
__device__ __forceinline__ void epi_to_lds(__bf16* lA, f32x4 acc[CI][MI], const void* bias,
                                           int n0, int lm, int lq, int f32) {
#pragma unroll
    for (int ci = 0; ci < CI; ++ci) {
        int n4 = n0 + ci * 16 + lq * 4;
        float b0 = loadF(bias, n4 + 0, f32), b1 = loadF(bias, n4 + 1, f32);
        float b2 = loadF(bias, n4 + 2, f32), b3 = loadF(bias, n4 + 3, f32);
#pragma unroll
        for (int mi = 0; mi < MI; ++mi) {
            int m = mi * 16 + lm;
            f32x4 a = acc[ci][mi];
            bf16x4 v;
            v[0] = (__bf16)fmaxf(a[0] + b0, 0.f);
            v[1] = (__bf16)fmaxf(a[1] + b1, 0.f);
            v[2] = (__bf16)fmaxf(a[2] + b2, 0.f);
            v[3] = (__bf16)fmaxf(a[3] + b3, 0.f);
            *(bf16x4*)(lA + m * 256 + (((n4 >> 3) ^ (m & 7)) << 3) + (n4 & 7)) = v;
        }
    }
}

// epilogue helper: full-line stores from swizzled LDS to Y; RW = rows per wave
template<int RW>
__device__ __forceinline__ void lds_to_global(const __bf16* lA, __bf16* __restrict__ Y,
                                              int bm, int w, int lane, int M_) {
    int half = lane >> 5;
    int cc = lane & 31;
#pragma unroll
    for (int it = 0; it < RW / 2; ++it) {
        int r = w * RW + it * 2 + half;
        int gm = bm + r;
        if (gm < M_) {
            bf16x8 v = *(const bf16x8*)(lA + r * 256 + ((cc ^ (r & 7)) << 3));
            *(bf16x8*)(Y + (size_t)gm * 256 + cc * 8) = v;
        }
    }
}

// ---------------- fused staging: lA[r] = H[bm+r] + sum_{dst(e)=bm+r} H[src(e)] ----------------
// 512 threads: 8 threads/row, fp32 accumulation in 32 regs, 2 passes over 128 rows.
// This sits in a narrow feasibility pocket (session-verified): fewer lanes/row doubles
// HBM fetch (r10); more passes serializes (r4); bigger register batching spills (r7/r11);
// gll-DMA and dense tables regress (r8/r6). Do not perturb without new evidence.
__device__ __forceinline__ void stage128_agg512(const __bf16* __restrict__ H, __bf16* lA,
                                                const int* __restrict__ offs,
                                                const int* __restrict__ deg,
                                                const int* __restrict__ elist,
                                                int bm, int t, int M_) {
    int tc = t & 7;            // col-group: bf16 cols tc*32 .. tc*32+31
    int rl = t >> 3;           // row within pass (0..63)
#pragma unroll 1
    for (int p = 0; p < 2; ++p) {
        int r = p * 64 + rl;
        int gr = bm + r;
        if (gr >= M_) gr = M_ - 1;
        const __bf16* self = H + (size_t)gr * 256 + tc * 32;
        float acc[32];
        {
            bf16x8 v0 = *(const bf16x8*)(self + 0);
            bf16x8 v1 = *(const bf16x8*)(self + 8);
            bf16x8 v2 = *(const bf16x8*)(self + 16);
            bf16x8 v3 = *(const bf16x8*)(self + 24);
#pragma unroll
            for (int j = 0; j < 8; ++j) {
                acc[j]      = (float)v0[j];
                acc[8 + j]  = (float)v1[j];
                acc[16 + j] = (float)v2[j];
                acc[24 + j] = (float)v3[j];
            }
        }
        int b = offs[gr], d = min(deg[gr], 1024);
        int e = 0;
        for (; e + 1 < d; e += 2) {
            int u0 = elist[b + e];
            int u1 = elist[b + e + 1];
            if ((unsigned)u0 >= (unsigned)MN) u0 = 0;
            if ((unsigned)u1 >= (unsigned)MN) u1 = 0;
            const __bf16* nb0 = H + (size_t)u0 * 256 + tc * 32;
            const __bf16* nb1 = H + (size_t)u1 * 256 + tc * 32;
            bf16x8 a0 = *(const bf16x8*)(nb0 + 0);
            bf16x8 a1 = *(const bf16x8*)(nb0 + 8);
            bf16x8 a2 = *(const bf16x8*)(nb0 + 16);
            bf16x8 a3 = *(const bf16x8*)(nb0 + 24);
            bf16x8 c0 = *(const bf16x8*)(nb1 + 0);
            bf16x8 c1 = *(const bf16x8*)(nb1 + 8);
            bf16x8 c2 = *(const bf16x8*)(nb1 + 16);
            bf16x8 c3 = *(const bf16x8*)(nb1 + 24);
#pragma unroll
            for (int j = 0; j < 8; ++j) {
                acc[j]      += (float)a0[j] + (float)c0[j];
                acc[8 + j]  += (float)a1[j] + (float)c1[j];
                acc[16 + j] += (float)a2[j] + (float)c2[j];
                acc[24 + j] += (float)a3[j] + (float)c3[j];
            }
        }
        if (e < d) {
            int u = elist[b + e];
            if ((unsigned)u >= (unsigned)MN) u = 0;
            const __bf16* nb = H + (size_t)u * 256 + tc * 32;
            bf16x8 n0 = *(const bf16x8*)(nb + 0);
            bf16x8 n1 = *(const bf16x8*)(nb + 8);
            bf16x8 n2 = *(const bf16x8*)(nb + 16);
            bf16x8 n3 = *(const bf16x8*)(nb + 24);
#pragma unroll
            for (int j = 0; j < 8; ++j) {
                acc[j]      += (float)n0[j];
                acc[8 + j]  += (float)n1[j];
                acc[16 + j] += (float)n2[j];
                acc[24 + j] += (float)n3[j];
            }
        }
#pragma unroll
        for (int q = 0; q < 4; ++q) {
            int c = tc * 4 + q;      // bf16x8-chunk index 0..31
            bf16x8 o;
#pragma unroll
            for (int j = 0; j < 8; ++j) o[j] = (__bf16)acc[q * 8 + j];
            *(bf16x8*)(lA + r * 256 + ((c ^ (r & 7)) << 3)) = o;
        }
    }
}

// ---------------- fused GIN layer: Y = relu( relu((H+agg)@Wa+ba) @ Wb + bb ) ----------------
// r3/r9-proven config: 128-row tile, 8 waves, ci=2, 2 blocks/CU. ~113us/layer floor.
// do_pool: last layer skips the Y write and segment-sums the tile into POOL (batch sorted).
__global__ __launch_bounds__(512, 4) void k_agg_mlp(
    const __bf16* __restrict__ H, const int* __restrict__ offs, const int* __restrict__ deg,
    const int* __restrict__ elist,
    const __bf16* __restrict__ WaT, const void* __restrict__ ba,
    const __bf16* __restrict__ WbT, const void* __restrict__ bb,
    __bf16* __restrict__ Y, const int* __restrict__ batch,
    float* __restrict__ pool, float* __restrict__ cntf, int do_pool,
    int M_, const int* __restrict__ flags) {
    __shared__ __align__(16) __bf16 lA[128 * 256];
    __shared__ int sbatch[128];
    int t = threadIdx.x;
    int f32 = flags[0];
    int bm = blockIdx.x * 128;
    int w = t >> 6, lane = t & 63, lm = lane & 15, lq = lane >> 4;
    int n0 = w * 32;

    stage128_agg512(H, lA, offs, deg, elist, bm, t, M_);
    if (do_pool && t < 128) {
        int gm = bm + t;
        sbatch[t] = (gm < M_) ? loadI(batch, gm, flags[2]) : -1;
    }
    __syncthreads();

    {
        f32x4 acc[2][8] = {};
        gemm_core<2, 8>(lA, WaT, n0, lm, lq, acc);
        __syncthreads();   // all lA reads done; safe to overwrite with mid
        epi_to_lds<2, 8>(lA, acc, ba, n0, lm, lq, f32);
    }
    __syncthreads();

    f32x4 acc2[2][8] = {};
    gemm_core<2, 8>(lA, WbT, n0, lm, lq, acc2);
    __syncthreads();       // all lA reads done; safe to overwrite with result
    epi_to_lds<2, 8>(lA, acc2, bb, n0, lm, lq, f32);
    __syncthreads();

    if (!do_pool) {
        lds_to_global<16>(lA, Y, bm, w, lane, M_);
    } else {
        // segment mean-pool straight from LDS: thread = (col, row-half)
        int c = t & 255;
        int h2 = t >> 8;
        int g = -1;
        float acc = 0.f, run = 0.f;
        int rbeg = h2 * 64;
        for (int r = rbeg; r < rbeg + 64; ++r) {
            int bg = sbatch[r];
            if (bg < 0) break;   // past M_ (batch sorted)
            if ((unsigned)bg >= (unsigned)NG) bg = 0;
            float v = (float)lA[r * 256 + (((c >> 3) ^ (r & 7)) << 3) + (c & 7)];
            if (bg != g) {
                if (g >= 0) {
                    atomicAdd(&pool[(size_t)g * 256 + c], acc);
                    if (c == 0) atomicAdd(&cntf[g], run);
                }
                g = bg; acc = 0.f; run = 0.f;
            }
            acc += v; run += 1.f;
        }
        if (g >= 0) {
            atomicAdd(&pool[(size_t)g * 256 + c], acc);
            if (c == 0) atomicAdd(&cntf[g], run);
        }
    }
}

// ---------------- layer-1 GEMM: staging computes 7->256 linear from AGG7 ----------------
// 512 threads: staging at 4 threads/row (chain 896 -> 448 FMAs); 8-wave ci=2 GEMM path.
__global__ __launch_bounds__(512, 4) void k_gemm1(
    const float* __restrict__ agg7, const void* __restrict__ W1a, const void* __restrict__ b1a,
    const __bf16* __restrict__ WT, const void* __restrict__ bias,
    __bf16* __restrict__ Y, int M_, const int* __restrict__ flags) {
    __shared__ __align__(16) __bf16 lA[128 * 256];
    __shared__ float sW[7 * 256];
    __shared__ float sB[256];
    int t = threadIdx.x;
    int f32 = flags[0];
    int bm = blockIdx.x * 128;
    int w = t >> 6, lane = t & 63, lm = lane & 15, lq = lane >> 4;
    int n0 = w * 32;

    if (t < 256) sB[t] = loadF(b1a, t, f32);
    for (int i = t; i < 7 * 256; i += 512) sW[i] = loadF(W1a, i, f32);
    __syncthreads();

    {
        int r = t >> 2;                  // 4 threads/row over 128 rows
        int gr = bm + r;
        if (gr >= M_) gr = M_ - 1;
        float a[7];
#pragma unroll
        for (int k = 0; k < 7; ++k) a[k] = agg7[(size_t)gr * 8 + k];
        int c0 = (t & 3) * 64;
#pragma unroll
        for (int s8 = 0; s8 < 8; ++s8) {
            bf16x8 o;
#pragma unroll
            for (int j = 0; j < 8; ++j) {
                int cc = c0 + s8 * 8 + j;
                float v = sB[cc];
#pragma unroll
                for (int k = 0; k < 7; ++k) v = fmaf(a[k], sW[k * 256 + cc], v);
                o[j] = (__bf16)fmaxf(v, 0.f);
            }
            int ch = (c0 >> 3) + s8;
            *(bf16x8*)(lA + r * 256 + ((ch ^ (r & 7)) << 3)) = o;
        }
    }
    __syncthreads();

    f32x4 acc[2][8] = {};
    gemm_core<2, 8>(lA, WT, n0, lm, lq, acc);
    __syncthreads();
    epi_to_lds<2, 8>(lA, acc, bias, n0, lm, lq, f32);
    __syncthreads();
    lds_to_global<16>(lA, Y, bm, w, lane, M_);
}

// ---------------- head, split-K (r9-proven): out[g] = relu(mean @ Wh1 + bh1) @ Wh2 + bh2 ----
// Per-graph block (6000-block TLP; r5 showed LDS-residency kills it); K=256 chain split
// across 4 thread-groups (chain 256 -> 64), partials reduced through LDS. Wh1 L2-served.
__global__ __launch_bounds__(512) void k_head(
    const float* __restrict__ pool, const float* __restrict__ cnt,
    const void* __restrict__ Wh1, const void* __restrict__ bh1,
    const void* __restrict__ Wh2, const void* __restrict__ bh2,
    void* __restrict__ outv, const int* __restrict__ flags) {
    int g = blockIdx.x, t = threadIdx.x;   // 512 threads
    int f32 = flags[0];
    __shared__ float p[256];
    __shared__ float hidp[4][128];
    __shared__ float hid[128];
    float inv = 1.0f / fmaxf(cnt[g], 1.0f);
    if (t < 256) p[t] = pool[(size_t)g * 256 + t] * inv;
    __syncthreads();
    {
        int n = t & 127, kh = t >> 7;      // kh in 0..3: K-chunk of 64
        int kb = kh * 64;
        float s = 0.f;
#pragma unroll 8
        for (int k = 0; k < 64; ++k)
            s = fmaf(p[kb + k], loadF(Wh1, (size_t)(kb + k) * 128 + n, f32), s);
        hidp[kh][n] = s;
    }
    __syncthreads();
    if (t < 128)
        hid[t] = fmaxf(hidp[0][t] + hidp[1][t] + hidp[2][t] + hidp[3][t]
                       + loadF(bh1, t, f32), 0.f);
    __syncthreads();
    if (t < 192) {
        int n3 = t >> 6, lane = t & 63;
        float o = hid[lane] * loadF(Wh2, (size_t)lane * 3 + n3, f32);
        o = fmaf(hid[lane + 64], loadF(Wh2, (size_t)(lane + 64) * 3 + n3, f32), o);
#pragma unroll
        for (int off = 32; off > 0; off >>= 1) o += __shfl_down(o, off, 64);
        if (lane == 0) {
            o += loadF(bh2, n3, f32);
            if (f32) ((float*)outv)[(size_t)g * 3 + n3] = o;
            else     ((__bf16*)outv)[(size_t)g * 3 + n3] = (__bf16)o;
        }
    }
}

// ---------------- launch ----------------
extern "C" void kernel_launch(void* const* d_in, const int* in_sizes, int n_in,
                              void* d_out, int out_size, void* d_ws, size_t ws_size,
                              hipStream_t stream) {
    const void* x     = d_in[0];
    const int*  ei    = (const int*)d_in[1];
    const int*  batch = (const int*)d_in[2];
    const void *W[4][2], *b[4][2];
    for (int l = 0; l < 4; ++l) {
        W[l][0] = d_in[3 + 4 * l];
        b[l][0] = d_in[4 + 4 * l];
        W[l][1] = d_in[5 + 4 * l];
        b[l][1] = d_in[6 + 4 * l];
    }
    const void* Wh1 = d_in[19];
    const void* bh1 = d_in[20];
    const void* Wh2 = d_in[21];
    const void* bh2 = d_in[22];

    char* p = (char*)d_ws;
    auto alloc = [&](size_t bytes) -> char* {
        char* r = p;
        p += (bytes + 255) & ~(size_t)255;
        return r;
    };
    __bf16* B1    = (__bf16*)alloc((size_t)MN * 256 * 2);   // 76.8 MB
    __bf16* B2    = (__bf16*)alloc((size_t)MN * 256 * 2);   // 76.8 MB
    __bf16* WT    = (__bf16*)alloc((size_t)7 * 256 * 256 * 2);
    float*  AGG7  = (float*)alloc((size_t)MN * 8 * 4);      // 4.8 MB
    int*    offs  = (int*)alloc((size_t)MN * 4);
    int*    cnt   = (int*)alloc((size_t)MN * 4);
    int*    elist = (int*)alloc((size_t)NEDGE * 4);
    int*    bsum  = (int*)alloc((size_t)NSCAN * 4);
    int*    bbase = (int*)alloc((size_t)NSCAN * 4);
    float*  POOL  = (float*)alloc((size_t)NG * 256 * 4);    // CNTF contiguous after
    float*  CNTF  = (float*)alloc((size_t)NG * 4);
    int*    flags = (int*)alloc(64);

    // ---- dtype probe ----
    k_probe<<<1, 256, 0, stream>>>(W[0][0], ei, batch, flags);

    // ---- transposed bf16 weights [n][k]: W1b, W2a, W2b, W3a, W3b, W4a, W4b ----
    k_cvtWT<<<7 * 256, 256, 0, stream>>>(W[0][1], W[1][0], W[1][1], W[2][0], W[2][1],
                                         W[3][0], W[3][1], WT, flags);

    // ---- CSR build (by dst) ----
    hipMemsetAsync(cnt, 0, (size_t)MN * 4, stream);
    k_deg<<<(NEDGE + 255) / 256, 256, 0, stream>>>(ei, cnt, NEDGE, flags);
    k_blksum<<<NSCAN, 256, 0, stream>>>(cnt, bsum, MN);
    k_scanb<<<1, 1024, 0, stream>>>(bsum, bbase, NSCAN);
    k_blkscan<<<NSCAN, 256, 0, stream>>>(cnt, bbase, offs, MN);
    hipMemsetAsync(cnt, 0, (size_t)MN * 4, stream);   // cursor
    k_fill<<<(NEDGE + 255) / 256, 256, 0, stream>>>(ei, offs, cnt, elist, NEDGE, flags);
    // after k_fill, cnt[v] == degree(v)

    // ---- zero pool accumulators (POOL + CNTF contiguous) ----
    hipMemsetAsync(POOL, 0, (size_t)NG * 256 * 4 + (size_t)NG * 4, stream);

    int gblocks = (MN + 127) / 128;

    // ---- layer 1: gather-7 + (lin1 fused into gemm1 staging) ----
    k_l1lite<<<(MN + 31) / 32, 256, 0, stream>>>(x, offs, cnt, elist, AGG7, flags, MN);
    k_gemm1<<<gblocks, 512, 0, stream>>>(AGG7, W[0][0], b[0][0], WT /*W1b^T*/, b[0][1],
                                         B1, MN, flags);

    // ---- layers 2..4: fused agg+MLP, ping-pong B1/B2; last layer pools in-epilogue ----
    __bf16* bin = B1;
    __bf16* bout = B2;
    for (int l = 1; l < 4; ++l) {
        const __bf16* WaT = WT + (size_t)(1 + 2 * (l - 1)) * 65536;
        const __bf16* WbT = WT + (size_t)(2 + 2 * (l - 1)) * 65536;
        int dp = (l == 3) ? 1 : 0;
        k_agg_mlp<<<gblocks, 512, 0, stream>>>(bin, offs, cnt, elist,
                                               WaT, b[l][0], WbT, b[l][1], bout,
                                               batch, POOL, CNTF, dp, MN, flags);
        __bf16* tmp = bin; bin = bout; bout = tmp;
    }

    // ---- split-K head ----
    k_head<<<NG, 512, 0, stream>>>(POOL, CNTF, Wh1, bh1, Wh2, bh2, d_out, flags);
}

// Round 16
// 531.042 us; speedup vs baseline: 1.0608x; 1.0248x over previous
//
#include <hip/hip_runtime.h>

using bf16x8 = __attribute__((ext_vector_type(8))) __bf16;
using bf16x4 = __attribute__((ext_vector_type(4))) __bf16;
using f32x4  = __attribute__((ext_vector_type(4))) float;

#define MN    150000
#define NEDGE 300000
#define NG    6000
#define NSCAN 586   // ceil(MN/256)

// ---------------- dual-dtype helpers ----------------
// flags[0]=1 -> float tensors are fp32 (else bf16)
// flags[1]=1 -> edge_index is int64 (else int32)
// flags[2]=1 -> batch is int64 (else int32)
__device__ __forceinline__ float loadF(const void* p, size_t i, int f32) {
    return f32 ? ((const float*)p)[i] : (float)((const __bf16*)p)[i];
}
__device__ __forceinline__ int loadI(const int* p, size_t i, int i64) {
    return i64 ? p[2 * i] : p[i];
}

// ---------------- dtype probe ----------------
__global__ void k_probe(const void* W1a, const int* ei, const int* batch, int* flags) {
    __shared__ int s_f32, s_einz, s_bnz;
    if (threadIdx.x == 0) { s_f32 = 0; s_einz = 0; s_bnz = 0; }
    __syncthreads();
    const unsigned short* w = (const unsigned short*)W1a;
    for (int i = threadIdx.x; i < 1792; i += 256) {
        int e = (w[i] >> 7) & 0xFF;
        if (e >= 0xF0) s_f32 = 1;   // impossible for genuine |w|<=0.38 bf16
    }
    for (int i = threadIdx.x; i < 2048; i += 256)
        if (ei[2 * i + 1] != 0) s_einz = 1;
    for (int i = threadIdx.x; i < 2048; i += 256)
        if (batch[75000 + 2 * i + 1] != 0) s_bnz = 1;
    __syncthreads();
    if (threadIdx.x == 0) {
        flags[0] = s_f32;
        flags[1] = s_einz ? 0 : 1;
        flags[2] = s_bnz ? 0 : 1;
    }
}

// all 7 weight transposes in one launch: Wt[j][n][k] = W[j][k][n]
__global__ void k_cvtWT(const void* W0, const void* W1, const void* W2, const void* W3,
                        const void* W4, const void* W5, const void* W6,
                        __bf16* __restrict__ Wt, const int* __restrict__ flags) {
    int j = blockIdx.x >> 8;
    int n = blockIdx.x & 255, k = threadIdx.x;
    const void* Ws[7] = {W0, W1, W2, W3, W4, W5, W6};
    Wt[(size_t)j * 65536 + (size_t)n * 256 + k] = (__bf16)loadF(Ws[j], (size_t)k * 256 + n, flags[0]);
}

// ---------------- CSR build (by dst) ----------------
__global__ void k_deg(const int* __restrict__ ei, int* __restrict__ cnt, int nE,
                      const int* __restrict__ flags) {
    int e = blockIdx.x * 256 + threadIdx.x;
    if (e >= nE) return;
    int i64 = flags[1];
    int d = loadI(ei, (size_t)nE + e, i64);
    if ((unsigned)d >= (unsigned)MN) d = 0;
    atomicAdd(&cnt[d], 1);
}
__global__ void k_blksum(const int* __restrict__ cnt, int* __restrict__ bsum, int n) {
    __shared__ int s[256];
    int t = threadIdx.x;
    int i = blockIdx.x * 256 + t;
    s[t] = (i < n) ? cnt[i] : 0;
    __syncthreads();
    for (int o = 128; o > 0; o >>= 1) {
        if (t < o) s[t] += s[t + o];
        __syncthreads();
    }
    if (t == 0) bsum[blockIdx.x] = s[0];
}
// parallel block-base scan: 1024 threads, Hillis-Steele over NSCAN elements
__global__ __launch_bounds__(1024) void k_scanb(const int* __restrict__ bsum,
                                                int* __restrict__ bbase, int nb) {
    __shared__ int s[1024];
    int t = threadIdx.x;
    int v = (t < nb) ? bsum[t] : 0;
    s[t] = v;
    __syncthreads();
#pragma unroll
    for (int o = 1; o < 1024; o <<= 1) {
        int x = (t >= o) ? s[t - o] : 0;
        __syncthreads();
        s[t] += x;
        __syncthreads();
    }
    if (t < nb) bbase[t] = s[t] - v;   // exclusive
}
__global__ void k_blkscan(const int* __restrict__ cnt, const int* __restrict__ bbase,
                          int* __restrict__ offs, int n) {
    __shared__ int s[256];
    int t = threadIdx.x;
    int i = blockIdx.x * 256 + t;
    int v = (i < n) ? cnt[i] : 0;
    s[t] = v;
    __syncthreads();
    for (int o = 1; o < 256; o <<= 1) {
        int x = (t >= o) ? s[t - o] : 0;
        __syncthreads();
        s[t] += x;
        __syncthreads();
    }
    if (i < n) offs[i] = bbase[blockIdx.x] + s[t] - v;
}
__global__ void k_fill(const int* __restrict__ ei, const int* __restrict__ offs,
                       int* __restrict__ cur, int* __restrict__ elist, int nE,
                       const int* __restrict__ flags) {
    int e = blockIdx.x * 256 + threadIdx.x;
    if (e >= nE) return;
    int i64 = flags[1];
    int s = loadI(ei, (size_t)e, i64);
    int d = loadI(ei, (size_t)nE + e, i64);
    if ((unsigned)s >= (unsigned)MN) s = 0;
    if ((unsigned)d >= (unsigned)MN) d = 0;
    int pos = offs[d] + atomicAdd(&cur[d], 1);
    // guard vs rocprof-replay corrupting stateful atomics (timed runs rebuild cleanly)
    if ((unsigned)pos < (unsigned)NEDGE) elist[pos] = s;
}

// ---------------- layer 1 lite: agg7 only -> AGG7 (fp32, padded to 8) ----------------
// 8 threads/row, one float per neighbor per thread (fully parallel across j) --
// fusing this into k_gemm1's 4-thread/row staging was 4x-redundant and regressed (r14).
__global__ __launch_bounds__(256) void k_l1lite(
    const void* __restrict__ x, const int* __restrict__ offs,
    const int* __restrict__ deg, const int* __restrict__ elist,
    float* __restrict__ agg7, const int* __restrict__ flags, int M_) {
    int f32 = flags[0];
    int t = threadIdx.x;
    int v = blockIdx.x * 32 + (t >> 3);
    int j = t & 7;
    if (v >= M_ || j >= 7) return;
    float s = loadF(x, (size_t)v * 7 + j, f32);
    int b = offs[v], d = min(deg[v], 1024);
    for (int e = 0; e < d; ++e) {
        int u = elist[b + e];
        if ((unsigned)u >= (unsigned)MN) u = 0;
        s += loadF(x, (size_t)u * 7 + j, f32);
    }
    agg7[(size_t)v * 8 + j] = s;
}

// ---------------- MFMA GEMM core, 128-row tile, CI x MI accumulator ----------------
// CI = 16-col groups per wave, MI = 16-row groups (128 rows -> MI=8). r3-proven body.
template<int CI, int MI>
__device__ __forceinline__ void gemm_core(const __bf16* lA, const __bf16* __restrict__ WT,
                                          int n0, int lm, int lq, f32x4 acc[CI][MI]) {
    const __bf16* wp = WT + (size_t)(n0 + lm) * 256 + lq * 8;
    bf16x8 wf[CI], wn[CI];
#pragma unroll
    for (int ci = 0; ci < CI; ++ci)
        wf[ci] = *(const bf16x8*)(wp + ci * 16 * 256);
#pragma unroll
    for (int kt = 0; kt < 8; ++kt) {
        if (kt < 7) {
#pragma unroll
            for (int ci = 0; ci < CI; ++ci)
                wn[ci] = *(const bf16x8*)(wp + ci * 16 * 256 + (kt + 1) * 32);
        }
        int sw = (((kt * 4 + lq) ^ (lm & 7)) << 3);
        bf16x8 xf[MI];
#pragma unroll
        for (int mi = 0; mi < MI; ++mi)
            xf[mi] = *(const bf16x8*)(lA + (mi * 16 + lm) * 256 + sw);
#pragma unroll
        for (int ci = 0; ci < CI; ++ci)
#pragma unroll
            for (int mi = 0; mi < MI; ++mi)
                acc[ci][mi] = __builtin_amdgcn_mfma_f32_16x16x32_bf16(
                    wf[ci], xf[mi], acc[ci][mi], 0, 0, 0);
#pragma unroll
        for (int ci = 0; ci < CI; ++ci) wf[ci] = wn[ci];
    }
}

// epilogue helper: write acc tile (relu(acc+bias)) into swizzled LDS
template<int CI, int MI>
__device__ __forceinline__ void epi_to_lds(__bf16* lA, f32x4 acc[CI][MI], const void* bias,
                                           int n0, int lm, int lq, int f32) {
#pragma unroll
    for (int ci = 0; ci < CI; ++ci) {
        int n4 = n0 + ci * 16 + lq * 4;
        float b0 = loadF(bias, n4 + 0, f32), b1 = loadF(bias, n4 + 1, f32);
        float b2 = loadF(bias, n4 + 2, f32), b3 = loadF(bias, n4 + 3, f32);
#pragma unroll
        for (int mi = 0; mi < MI; ++mi) {
            int m = mi * 16 + lm;
            f32x4 a = acc[ci][mi];
            bf16x4 v;
            v[0] = (__bf16)fmaxf(a[0] + b0, 0.f);
            v[1] = (__bf16)fmaxf(a[1] + b1, 0.f);
            v[2] = (__bf16)fmaxf(a[2] + b2, 0.f);
            v[3] = (__bf16)fmaxf(a[3] + b3, 0.f);
            *(bf16x4*)(lA + m * 256 + (((n4 >> 3) ^ (m & 7)) << 3) + (n4 & 7)) = v;
        }
    }
}

// epilogue helper: full-line stores from swizzled LDS to Y; RW = rows per wave
template<int RW>
__device__ __forceinline__ void lds_to_global(const __bf16* lA, __bf16* __restrict__ Y,
                                              int bm, int w, int lane, int M_) {
    int half = lane >> 5;
    int cc = lane & 31;
#pragma unroll
    for (int it = 0; it < RW / 2; ++it) {
        int r = w * RW + it * 2 + half;
        int gm = bm + r;
        if (gm < M_) {
            bf16x8 v = *(const bf16x8*)(lA + r * 256 + ((cc ^ (r & 7)) << 3));
            *(bf16x8*)(Y + (size_t)gm * 256 + cc * 8) = v;
        }
    }
}

// ---------------- fused staging: lA[r] = H[bm+r] + sum_{dst(e)=bm+r} H[src(e)] ----------------
// 512 threads: 8 threads/row, fp32 accumulation in 32 regs, 2 passes over 128 rows.
// This sits in a narrow feasibility pocket (session-verified): fewer lanes/row doubles
// HBM fetch (r10); more passes serializes (r4); bigger register batching spills (r7/r11);
// gll-DMA and dense tables regress (r8/r6). Do not perturb without new evidence.
__device__ __forceinline__ void stage128_agg512(const __bf16* __restrict__ H, __bf16* lA,
                                                const int* __restrict__ offs,
                                                const int* __restrict__ deg,
                                                const int* __restrict__ elist,
                                                int bm, int t, int M_) {
    int tc = t & 7;            // col-group: bf16 cols tc*32 .. tc*32+31
    int rl = t >> 3;           // row within pass (0..63)
#pragma unroll 1
    for (int p = 0; p < 2; ++p) {
        int r = p * 64 + rl;
        int gr = bm + r;
        if (gr >= M_) gr = M_ - 1;
        const __bf16* self = H + (size_t)gr * 256 + tc * 32;
        float acc[32];
        {
            bf16x8 v0 = *(const bf16x8*)(self + 0);
            bf16x8 v1 = *(const bf16x8*)(self + 8);
            bf16x8 v2 = *(const bf16x8*)(self + 16);
            bf16x8 v3 = *(const bf16x8*)(self + 24);
#pragma unroll
            for (int j = 0; j < 8; ++j) {
                acc[j]      = (float)v0[j];
                acc[8 + j]  = (float)v1[j];
                acc[16 + j] = (float)v2[j];
                acc[24 + j] = (float)v3[j];
            }
        }
        int b = offs[gr], d = min(deg[gr], 1024);
        int e = 0;
        for (; e + 1 < d; e += 2) {
            int u0 = elist[b + e];
            int u1 = elist[b + e + 1];
            if ((unsigned)u0 >= (unsigned)MN) u0 = 0;
            if ((unsigned)u1 >= (unsigned)MN) u1 = 0;
            const __bf16* nb0 = H + (size_t)u0 * 256 + tc * 32;
            const __bf16* nb1 = H + (size_t)u1 * 256 + tc * 32;
            bf16x8 a0 = *(const bf16x8*)(nb0 + 0);
            bf16x8 a1 = *(const bf16x8*)(nb0 + 8);
            bf16x8 a2 = *(const bf16x8*)(nb0 + 16);
            bf16x8 a3 = *(const bf16x8*)(nb0 + 24);
            bf16x8 c0 = *(const bf16x8*)(nb1 + 0);
            bf16x8 c1 = *(const bf16x8*)(nb1 + 8);
            bf16x8 c2 = *(const bf16x8*)(nb1 + 16);
            bf16x8 c3 = *(const bf16x8*)(nb1 + 24);
#pragma unroll
            for (int j = 0; j < 8; ++j) {
                acc[j]      += (float)a0[j] + (float)c0[j];
                acc[8 + j]  += (float)a1[j] + (float)c1[j];
                acc[16 + j] += (float)a2[j] + (float)c2[j];
                acc[24 + j] += (float)a3[j] + (float)c3[j];
            }
        }
        if (e < d) {
            int u = elist[b + e];
            if ((unsigned)u >= (unsigned)MN) u = 0;
            const __bf16* nb = H + (size_t)u * 256 + tc * 32;
            bf16x8 n0 = *(const bf16x8*)(nb + 0);
            bf16x8 n1 = *(const bf16x8*)(nb + 8);
            bf16x8 n2 = *(const bf16x8*)(nb + 16);
            bf16x8 n3 = *(const bf16x8*)(nb + 24);
#pragma unroll
            for (int j = 0; j < 8; ++j) {
                acc[j]      += (float)n0[j];
                acc[8 + j]  += (float)n1[j];
                acc[16 + j] += (float)n2[j];
                acc[24 + j] += (float)n3[j];
            }
        }
#pragma unroll
        for (int q = 0; q < 4; ++q) {
            int c = tc * 4 + q;      // bf16x8-chunk index 0..31
            bf16x8 o;
#pragma unroll
            for (int j = 0; j < 8; ++j) o[j] = (__bf16)acc[q * 8 + j];
            *(bf16x8*)(lA + r * 256 + ((c ^ (r & 7)) << 3)) = o;
        }
    }
}

// ---------------- fused GIN layer: Y = relu( relu((H+agg)@Wa+ba) @ Wb + bb ) ----------------
// r3/r9-proven config: 128-row tile, 8 waves, ci=2, 2 blocks/CU. ~113us/layer floor.
// do_pool: last layer skips the Y write and segment-sums the tile into POOL (batch sorted).
__global__ __launch_bounds__(512, 4) void k_agg_mlp(
    const __bf16* __restrict__ H, const int* __restrict__ offs, const int* __restrict__ deg,
    const int* __restrict__ elist,
    const __bf16* __restrict__ WaT, const void* __restrict__ ba,
    const __bf16* __restrict__ WbT, const void* __restrict__ bb,
    __bf16* __restrict__ Y, const int* __restrict__ batch,
    float* __restrict__ pool, float* __restrict__ cntf, int do_pool,
    int M_, const int* __restrict__ flags) {
    __shared__ __align__(16) __bf16 lA[128 * 256];
    __shared__ int sbatch[128];
    int t = threadIdx.x;
    int f32 = flags[0];
    int bm = blockIdx.x * 128;
    int w = t >> 6, lane = t & 63, lm = lane & 15, lq = lane >> 4;
    int n0 = w * 32;

    stage128_agg512(H, lA, offs, deg, elist, bm, t, M_);
    if (do_pool && t < 128) {
        int gm = bm + t;
        sbatch[t] = (gm < M_) ? loadI(batch, gm, flags[2]) : -1;
    }
    __syncthreads();

    {
        f32x4 acc[2][8] = {};
        gemm_core<2, 8>(lA, WaT, n0, lm, lq, acc);
        __syncthreads();   // all lA reads done; safe to overwrite with mid
        epi_to_lds<2, 8>(lA, acc, ba, n0, lm, lq, f32);
    }
    __syncthreads();

    f32x4 acc2[2][8] = {};
    gemm_core<2, 8>(lA, WbT, n0, lm, lq, acc2);
    __syncthreads();       // all lA reads done; safe to overwrite with result
    epi_to_lds<2, 8>(lA, acc2, bb, n0, lm, lq, f32);
    __syncthreads();

    if (!do_pool) {
        lds_to_global<16>(lA, Y, bm, w, lane, M_);
    } else {
        // segment mean-pool straight from LDS: thread = (col, row-half)
        int c = t & 255;
        int h2 = t >> 8;
        int g = -1;
        float acc = 0.f, run = 0.f;
        int rbeg = h2 * 64;
        for (int r = rbeg; r < rbeg + 64; ++r) {
            int bg = sbatch[r];
            if (bg < 0) break;   // past M_ (batch sorted)
            if ((unsigned)bg >= (unsigned)NG) bg = 0;
            float v = (float)lA[r * 256 + (((c >> 3) ^ (r & 7)) << 3) + (c & 7)];
            if (bg != g) {
                if (g >= 0) {
                    atomicAdd(&pool[(size_t)g * 256 + c], acc);
                    if (c == 0) atomicAdd(&cntf[g], run);
                }
                g = bg; acc = 0.f; run = 0.f;
            }
            acc += v; run += 1.f;
        }
        if (g >= 0) {
            atomicAdd(&pool[(size_t)g * 256 + c], acc);
            if (c == 0) atomicAdd(&cntf[g], run);
        }
    }
}

// ---------------- layer-1 GEMM: staging computes 7->256 linear from AGG7 ----------------
// 512 threads: staging at 4 threads/row (chain 896 -> 448 FMAs); 8-wave ci=2 GEMM path.
__global__ __launch_bounds__(512, 4) void k_gemm1(
    const float* __restrict__ agg7, const void* __restrict__ W1a, const void* __restrict__ b1a,
    const __bf16* __restrict__ WT, const void* __restrict__ bias,
    __bf16* __restrict__ Y, int M_, const int* __restrict__ flags) {
    __shared__ __align__(16) __bf16 lA[128 * 256];
    __shared__ float sW[7 * 256];
    __shared__ float sB[256];
    int t = threadIdx.x;
    int f32 = flags[0];
    int bm = blockIdx.x * 128;
    int w = t >> 6, lane = t & 63, lm = lane & 15, lq = lane >> 4;
    int n0 = w * 32;

    if (t < 256) sB[t] = loadF(b1a, t, f32);
    for (int i = t; i < 7 * 256; i += 512) sW[i] = loadF(W1a, i, f32);
    __syncthreads();

    {
        int r = t >> 2;                  // 4 threads/row over 128 rows
        int gr = bm + r;
        if (gr >= M_) gr = M_ - 1;
        float a[7];
#pragma unroll
        for (int k = 0; k < 7; ++k) a[k] = agg7[(size_t)gr * 8 + k];
        int c0 = (t & 3) * 64;
#pragma unroll
        for (int s8 = 0; s8 < 8; ++s8) {
            bf16x8 o;
#pragma unroll
            for (int j = 0; j < 8; ++j) {
                int cc = c0 + s8 * 8 + j;
                float v = sB[cc];
#pragma unroll
                for (int k = 0; k < 7; ++k) v = fmaf(a[k], sW[k * 256 + cc], v);
                o[j] = (__bf16)fmaxf(v, 0.f);
            }
            int ch = (c0 >> 3) + s8;
            *(bf16x8*)(lA + r * 256 + ((ch ^ (r & 7)) << 3)) = o;
        }
    }
    __syncthreads();

    f32x4 acc[2][8] = {};
    gemm_core<2, 8>(lA, WT, n0, lm, lq, acc);
    __syncthreads();
    epi_to_lds<2, 8>(lA, acc, bias, n0, lm, lq, f32);
    __syncthreads();
    lds_to_global<16>(lA, Y, bm, w, lane, M_);
}

// ---------------- head, split-K, 2 graphs/block: out[g] = relu(mean@Wh1+bh1)@Wh2+bh2 ----
// Each Wh1 element is loaded once and FMA'd for BOTH graphs -> Wh1 L2 traffic halves
// (786 MB -> 393 MB) while TLP stays high (3000 blocks; r5 showed 750 blocks+LDS kills it).
// Same split-K chain (64 FMAs); output stage runs both graphs on wave-aligned 64-lane groups.
__global__ __launch_bounds__(512) void k_head(
    const float* __restrict__ pool, const float* __restrict__ cnt,
    const void* __restrict__ Wh1, const void* __restrict__ bh1,
    const void* __restrict__ Wh2, const void* __restrict__ bh2,
    void* __restrict__ outv, const int* __restrict__ flags) {
    int g0 = blockIdx.x * 2, t = threadIdx.x;   // 512 threads, 2 graphs
    int f32 = flags[0];
    __shared__ float p[2][256];
    __shared__ float hidp[2][4][128];
    __shared__ float hid[2][128];
    {
        int gl = t >> 8, k = t & 255;           // 512 threads cover 2x256
        float inv = 1.0f / fmaxf(cnt[g0 + gl], 1.0f);
        p[gl][k] = pool[(size_t)(g0 + gl) * 256 + k] * inv;
    }
    __syncthreads();
    {
        int n = t & 127, kh = t >> 7;           // kh in 0..3: K-chunk of 64
        int kb = kh * 64;
        float s0 = 0.f, s1 = 0.f;
#pragma unroll 8
        for (int k = 0; k < 64; ++k) {
            float wv = loadF(Wh1, (size_t)(kb + k) * 128 + n, f32);
            s0 = fmaf(p[0][kb + k], wv, s0);
            s1 = fmaf(p[1][kb + k], wv, s1);
        }
        hidp[0][kh][n] = s0;
        hidp[1][kh][n] = s1;
    }
    __syncthreads();
    if (t < 256) {
        int gl = t >> 7, n = t & 127;
        hid[gl][n] = fmaxf(hidp[gl][0][n] + hidp[gl][1][n] + hidp[gl][2][n] + hidp[gl][3][n]
                           + loadF(bh1, n, f32), 0.f);
    }
    __syncthreads();
    if (t < 384) {
        int gl = (t >= 192) ? 1 : 0;            // [0,192)=waves 0-2, [192,384)=waves 3-5
        int tt = t - 192 * gl;
        int n3 = tt >> 6, lane = tt & 63;       // == t & 63 (192 = 3 waves): wave-aligned
        float o = hid[gl][lane] * loadF(Wh2, (size_t)lane * 3 + n3, f32);
        o = fmaf(hid[gl][lane + 64], loadF(Wh2, (size_t)(lane + 64) * 3 + n3, f32), o);
#pragma unroll
        for (int off = 32; off > 0; off >>= 1) o += __shfl_down(o, off, 64);
        if (lane == 0) {
            o += loadF(bh2, n3, f32);
            int g = g0 + gl;
            if (f32) ((float*)outv)[(size_t)g * 3 + n3] = o;
            else     ((__bf16*)outv)[(size_t)g * 3 + n3] = (__bf16)o;
        }
    }
}

// ---------------- launch ----------------
extern "C" void kernel_launch(void* const* d_in, const int* in_sizes, int n_in,
                              void* d_out, int out_size, void* d_ws, size_t ws_size,
                              hipStream_t stream) {
    const void* x     = d_in[0];
    const int*  ei    = (const int*)d_in[1];
    const int*  batch = (const int*)d_in[2];
    const void *W[4][2], *b[4][2];
    for (int l = 0; l < 4; ++l) {
        W[l][0] = d_in[3 + 4 * l];
        b[l][0] = d_in[4 + 4 * l];
        W[l][1] = d_in[5 + 4 * l];
        b[l][1] = d_in[6 + 4 * l];
    }
    const void* Wh1 = d_in[19];
    const void* bh1 = d_in[20];
    const void* Wh2 = d_in[21];
    const void* bh2 = d_in[22];

    char* p = (char*)d_ws;
    auto alloc = [&](size_t bytes) -> char* {
        char* r = p;
        p += (bytes + 255) & ~(size_t)255;
        return r;
    };
    __bf16* B1    = (__bf16*)alloc((size_t)MN * 256 * 2);   // 76.8 MB
    __bf16* B2    = (__bf16*)alloc((size_t)MN * 256 * 2);   // 76.8 MB
    __bf16* WT    = (__bf16*)alloc((size_t)7 * 256 * 256 * 2);
    float*  AGG7  = (float*)alloc((size_t)MN * 8 * 4);      // 4.8 MB
    int*    offs  = (int*)alloc((size_t)MN * 4);
    int*    cnt   = (int*)alloc((size_t)MN * 4);
    int*    elist = (int*)alloc((size_t)NEDGE * 4);
    int*    bsum  = (int*)alloc((size_t)NSCAN * 4);
    int*    bbase = (int*)alloc((size_t)NSCAN * 4);
    float*  POOL  = (float*)alloc((size_t)NG * 256 * 4);    // CNTF contiguous after
    float*  CNTF  = (float*)alloc((size_t)NG * 4);
    int*    flags = (int*)alloc(64);

    // ---- dtype probe ----
    k_probe<<<1, 256, 0, stream>>>(W[0][0], ei, batch, flags);

    // ---- transposed bf16 weights [n][k]: W1b, W2a, W2b, W3a, W3b, W4a, W4b ----
    k_cvtWT<<<7 * 256, 256, 0, stream>>>(W[0][1], W[1][0], W[1][1], W[2][0], W[2][1],
                                         W[3][0], W[3][1], WT, flags);

    // ---- CSR build (by dst) ----
    hipMemsetAsync(cnt, 0, (size_t)MN * 4, stream);
    k_deg<<<(NEDGE + 255) / 256, 256, 0, stream>>>(ei, cnt, NEDGE, flags);
    k_blksum<<<NSCAN, 256, 0, stream>>>(cnt, bsum, MN);
    k_scanb<<<1, 1024, 0, stream>>>(bsum, bbase, NSCAN);
    k_blkscan<<<NSCAN, 256, 0, stream>>>(cnt, bbase, offs, MN);
    hipMemsetAsync(cnt, 0, (size_t)MN * 4, stream);   // cursor
    k_fill<<<(NEDGE + 255) / 256, 256, 0, stream>>>(ei, offs, cnt, elist, NEDGE, flags);
    // after k_fill, cnt[v] == degree(v)

    // ---- zero pool accumulators (POOL + CNTF contiguous) ----
    hipMemsetAsync(POOL, 0, (size_t)NG * 256 * 4 + (size_t)NG * 4, stream);

    int gblocks = (MN + 127) / 128;

    // ---- layer 1: gather-7 + (lin1 fused into gemm1 staging) ----
    k_l1lite<<<(MN + 31) / 32, 256, 0, stream>>>(x, offs, cnt, elist, AGG7, flags, MN);
    k_gemm1<<<gblocks, 512, 0, stream>>>(AGG7, W[0][0], b[0][0], WT /*W1b^T*/, b[0][1],
                                         B1, MN, flags);

    // ---- layers 2..4: fused agg+MLP, ping-pong B1/B2; last layer pools in-epilogue ----
    __bf16* bin = B1;
    __bf16* bout = B2;
    for (int l = 1; l < 4; ++l) {
        const __bf16* WaT = WT + (size_t)(1 + 2 * (l - 1)) * 65536;
        const __bf16* WbT = WT + (size_t)(2 + 2 * (l - 1)) * 65536;
        int dp = (l == 3) ? 1 : 0;
        k_agg_mlp<<<gblocks, 512, 0, stream>>>(bin, offs, cnt, elist,
                                               WaT, b[l][0], WbT, b[l][1], bout,
                                               batch, POOL, CNTF, dp, MN, flags);
        __bf16* tmp = bin; bin = bout; bout = tmp;
    }

    // ---- split-K head, 2 graphs/block ----
    k_head<<<NG / 2, 512, 0, stream>>>(POOL, CNTF, Wh1, bh1, Wh2, bh2, d_out, flags);
}

// Round 17
// 529.253 us; speedup vs baseline: 1.0644x; 1.0034x over previous
//
#include <hip/hip_runtime.h>

using bf16x8 = __attribute__((ext_vector_type(8))) __bf16;
using bf16x4 = __attribute__((ext_vector_type(4))) __bf16;
using f32x4  = __attribute__((ext_vector_type(4))) float;

#define MN    150000
#define NEDGE 300000
#define NG    6000
#define NSCAN 586   // ceil(MN/256)

// ---------------- dual-dtype helpers ----------------
// flags[0]=1 -> float tensors are fp32 (else bf16)
// flags[1]=1 -> edge_index is int64 (else int32)
// flags[2]=1 -> batch is int64 (else int32)
__device__ __forceinline__ float loadF(const void* p, size_t i, int f32) {
    return f32 ? ((const float*)p)[i] : (float)((const __bf16*)p)[i];
}
__device__ __forceinline__ int loadI(const int* p, size_t i, int i64) {
    return i64 ? p[2 * i] : p[i];
}

// ---------------- dtype probe ----------------
__global__ void k_probe(const void* W1a, const int* ei, const int* batch, int* flags) {
    __shared__ int s_f32, s_einz, s_bnz;
    if (threadIdx.x == 0) { s_f32 = 0; s_einz = 0; s_bnz = 0; }
    __syncthreads();
    const unsigned short* w = (const unsigned short*)W1a;
    for (int i = threadIdx.x; i < 1792; i += 256) {
        int e = (w[i] >> 7) & 0xFF;
        if (e >= 0xF0) s_f32 = 1;   // impossible for genuine |w|<=0.38 bf16
    }
    for (int i = threadIdx.x; i < 2048; i += 256)
        if (ei[2 * i + 1] != 0) s_einz = 1;
    for (int i = threadIdx.x; i < 2048; i += 256)
        if (batch[75000 + 2 * i + 1] != 0) s_bnz = 1;
    __syncthreads();
    if (threadIdx.x == 0) {
        flags[0] = s_f32;
        flags[1] = s_einz ? 0 : 1;
        flags[2] = s_bnz ? 0 : 1;
    }
}

// all 7 weight transposes in one launch: Wt[j][n][k] = W[j][k][n]
__global__ void k_cvtWT(const void* W0, const void* W1, const void* W2, const void* W3,
                        const void* W4, const void* W5, const void* W6,
                        __bf16* __restrict__ Wt, const int* __restrict__ flags) {
    int j = blockIdx.x >> 8;
    int n = blockIdx.x & 255, k = threadIdx.x;
    const void* Ws[7] = {W0, W1, W2, W3, W4, W5, W6};
    Wt[(size_t)j * 65536 + (size_t)n * 256 + k] = (__bf16)loadF(Ws[j], (size_t)k * 256 + n, flags[0]);
}

// ---------------- CSR build (by dst) ----------------
__global__ void k_deg(const int* __restrict__ ei, int* __restrict__ cnt, int nE,
                      const int* __restrict__ flags) {
    int e = blockIdx.x * 256 + threadIdx.x;
    if (e >= nE) return;
    int i64 = flags[1];
    int d = loadI(ei, (size_t)nE + e, i64);
    if ((unsigned)d >= (unsigned)MN) d = 0;
    atomicAdd(&cnt[d], 1);
}
__global__ void k_blksum(const int* __restrict__ cnt, int* __restrict__ bsum, int n) {
    __shared__ int s[256];
    int t = threadIdx.x;
    int i = blockIdx.x * 256 + t;
    s[t] = (i < n) ? cnt[i] : 0;
    __syncthreads();
    for (int o = 128; o > 0; o >>= 1) {
        if (t < o) s[t] += s[t + o];
        __syncthreads();
    }
    if (t == 0) bsum[blockIdx.x] = s[0];
}
// parallel block-base scan: 1024 threads, Hillis-Steele over NSCAN elements
__global__ __launch_bounds__(1024) void k_scanb(const int* __restrict__ bsum,
                                                int* __restrict__ bbase, int nb) {
    __shared__ int s[1024];
    int t = threadIdx.x;
    int v = (t < nb) ? bsum[t] : 0;
    s[t] = v;
    __syncthreads();
#pragma unroll
    for (int o = 1; o < 1024; o <<= 1) {
        int x = (t >= o) ? s[t - o] : 0;
        __syncthreads();
        s[t] += x;
        __syncthreads();
    }
    if (t < nb) bbase[t] = s[t] - v;   // exclusive
}
__global__ void k_blkscan(const int* __restrict__ cnt, const int* __restrict__ bbase,
                          int* __restrict__ offs, int n) {
    __shared__ int s[256];
    int t = threadIdx.x;
    int i = blockIdx.x * 256 + t;
    int v = (i < n) ? cnt[i] : 0;
    s[t] = v;
    __syncthreads();
    for (int o = 1; o < 256; o <<= 1) {
        int x = (t >= o) ? s[t - o] : 0;
        __syncthreads();
        s[t] += x;
        __syncthreads();
    }
    if (i < n) offs[i] = bbase[blockIdx.x] + s[t] - v;
}
__global__ void k_fill(const int* __restrict__ ei, const int* __restrict__ offs,
                       int* __restrict__ cur, int* __restrict__ elist, int nE,
                       const int* __restrict__ flags) {
    int e = blockIdx.x * 256 + threadIdx.x;
    if (e >= nE) return;
    int i64 = flags[1];
    int s = loadI(ei, (size_t)e, i64);
    int d = loadI(ei, (size_t)nE + e, i64);
    if ((unsigned)s >= (unsigned)MN) s = 0;
    if ((unsigned)d >= (unsigned)MN) d = 0;
    int pos = offs[d] + atomicAdd(&cur[d], 1);
    // guard vs rocprof-replay corrupting stateful atomics (timed runs rebuild cleanly)
    if ((unsigned)pos < (unsigned)NEDGE) elist[pos] = s;
}

// ---------------- layer 1 lite: agg7 only -> AGG7 (fp32, padded to 8) ----------------
// 8 threads/row, one float per neighbor per thread (fully parallel across j) --
// fusing this into k_gemm1's 4-thread/row staging was 4x-redundant and regressed (r14).
__global__ __launch_bounds__(256) void k_l1lite(
    const void* __restrict__ x, const int* __restrict__ offs,
    const int* __restrict__ deg, const int* __restrict__ elist,
    float* __restrict__ agg7, const int* __restrict__ flags, int M_) {
    int f32 = flags[0];
    int t = threadIdx.x;
    int v = blockIdx.x * 32 + (t >> 3);
    int j = t & 7;
    if (v >= M_ || j >= 7) return;
    float s = loadF(x, (size_t)v * 7 + j, f32);
    int b = offs[v], d = min(deg[v], 1024);
    for (int e = 0; e < d; ++e) {
        int u = elist[b + e];
        if ((unsigned)u >= (unsigned)MN) u = 0;
        s += loadF(x, (size_t)u * 7 + j, f32);
    }
    agg7[(size_t)v * 8 + j] = s;
}

// ---------------- MFMA GEMM core, 128-row tile, CI x MI accumulator ----------------
// CI = 16-col groups per wave, MI = 16-row groups (128 rows -> MI=8). r3-proven body.
template<int CI, int MI>
__device__ __forceinline__ void gemm_core(const __bf16* lA, const __bf16* __restrict__ WT,
                                          int n0, int lm, int lq, f32x4 acc[CI][MI]) {
    const __bf16* wp = WT + (size_t)(n0 + lm) * 256 + lq * 8;
    bf16x8 wf[CI], wn[CI];
#pragma unroll
    for (int ci = 0; ci < CI; ++ci)
        wf[ci] = *(const bf16x8*)(wp + ci * 16 * 256);
#pragma unroll
    for (int kt = 0; kt < 8; ++kt) {
        if (kt < 7) {
#pragma unroll
            for (int ci = 0; ci < CI; ++ci)
                wn[ci] = *(const bf16x8*)(wp + ci * 16 * 256 + (kt + 1) * 32);
        }
        int sw = (((kt * 4 + lq) ^ (lm & 7)) << 3);
        bf16x8 xf[MI];
#pragma unroll
        for (int mi = 0; mi < MI; ++mi)
            xf[mi] = *(const bf16x8*)(lA + (mi * 16 + lm) * 256 + sw);
#pragma unroll
        for (int ci = 0; ci < CI; ++ci)
#pragma unroll
            for (int mi = 0; mi < MI; ++mi)
                acc[ci][mi] = __builtin_amdgcn_mfma_f32_16x16x32_bf16(
                    wf[ci], xf[mi], acc[ci][mi], 0, 0, 0);
#pragma unroll
        for (int ci = 0; ci < CI; ++ci) wf[ci] = wn[ci];
    }
}

// epilogue helper: write acc tile (relu(acc+bias)) into swizzled LDS
template<int CI, int MI>
__device__ __forceinline__ void epi_to_lds(__bf16* lA, f32x4 acc[CI][MI], const void* bias,
                                           int n0, int lm, int lq, int f32) {
#pragma unroll
    for (int ci = 0; ci < CI; ++ci) {
        int n4 = n0 + ci * 16 + lq * 4;
        float b0 = loadF(bias, n4 + 0, f32), b1 = loadF(bias, n4 + 1, f32);
        float b2 = loadF(bias, n4 + 2, f32), b3 = loadF(bias, n4 + 3, f32);
#pragma unroll
        for (int mi = 0; mi < MI; ++mi) {
            int m = mi * 16 + lm;
            f32x4 a = acc[ci][mi];
            bf16x4 v;
            v[0] = (__bf16)fmaxf(a[0] + b0, 0.f);
            v[1] = (__bf16)fmaxf(a[1] + b1, 0.f);
            v[2] = (__bf16)fmaxf(a[2] + b2, 0.f);
            v[3] = (__bf16)fmaxf(a[3] + b3, 0.f);
            *(bf16x4*)(lA + m * 256 + (((n4 >> 3) ^ (m & 7)) << 3) + (n4 & 7)) = v;
        }
    }
}

// epilogue helper: full-line stores from swizzled LDS to Y; RW = rows per wave
template<int RW>
__device__ __forceinline__ void lds_to_global(const __bf16* lA, __bf16* __restrict__ Y,
                                              int bm, int w, int lane, int M_) {
    int half = lane >> 5;
    int cc = lane & 31;
#pragma unroll
    for (int it = 0; it < RW / 2; ++it) {
        int r = w * RW + it * 2 + half;
        int gm = bm + r;
        if (gm < M_) {
            bf16x8 v = *(const bf16x8*)(lA + r * 256 + ((cc ^ (r & 7)) << 3));
            *(bf16x8*)(Y + (size_t)gm * 256 + cc * 8) = v;
        }
    }
}

// ---------------- fused staging: lA[r] = H[bm+r] + sum_{dst(e)=bm+r} H[src(e)] ----------------
// 512 threads: 8 threads/row, fp32 accumulation in 32 regs, 2 passes over 128 rows.
// This sits in a narrow feasibility pocket (session-verified): fewer lanes/row doubles
// HBM fetch (r10); more passes serializes (r4); bigger register batching spills (r7/r11);
// gll-DMA and dense tables regress (r8/r6). Do not perturb without new evidence.
__device__ __forceinline__ void stage128_agg512(const __bf16* __restrict__ H, __bf16* lA,
                                                const int* __restrict__ offs,
                                                const int* __restrict__ deg,
                                                const int* __restrict__ elist,
                                                int bm, int t, int M_) {
    int tc = t & 7;            // col-group: bf16 cols tc*32 .. tc*32+31
    int rl = t >> 3;           // row within pass (0..63)
#pragma unroll 1
    for (int p = 0; p < 2; ++p) {
        int r = p * 64 + rl;
        int gr = bm + r;
        if (gr >= M_) gr = M_ - 1;
        const __bf16* self = H + (size_t)gr * 256 + tc * 32;
        float acc[32];
        {
            bf16x8 v0 = *(const bf16x8*)(self + 0);
            bf16x8 v1 = *(const bf16x8*)(self + 8);
            bf16x8 v2 = *(const bf16x8*)(self + 16);
            bf16x8 v3 = *(const bf16x8*)(self + 24);
#pragma unroll
            for (int j = 0; j < 8; ++j) {
                acc[j]      = (float)v0[j];
                acc[8 + j]  = (float)v1[j];
                acc[16 + j] = (float)v2[j];
                acc[24 + j] = (float)v3[j];
            }
        }
        int b = offs[gr], d = min(deg[gr], 1024);
        int e = 0;
        for (; e + 1 < d; e += 2) {
            int u0 = elist[b + e];
            int u1 = elist[b + e + 1];
            if ((unsigned)u0 >= (unsigned)MN) u0 = 0;
            if ((unsigned)u1 >= (unsigned)MN) u1 = 0;
            const __bf16* nb0 = H + (size_t)u0 * 256 + tc * 32;
            const __bf16* nb1 = H + (size_t)u1 * 256 + tc * 32;
            bf16x8 a0 = *(const bf16x8*)(nb0 + 0);
            bf16x8 a1 = *(const bf16x8*)(nb0 + 8);
            bf16x8 a2 = *(const bf16x8*)(nb0 + 16);
            bf16x8 a3 = *(const bf16x8*)(nb0 + 24);
            bf16x8 c0 = *(const bf16x8*)(nb1 + 0);
            bf16x8 c1 = *(const bf16x8*)(nb1 + 8);
            bf16x8 c2 = *(const bf16x8*)(nb1 + 16);
            bf16x8 c3 = *(const bf16x8*)(nb1 + 24);
#pragma unroll
            for (int j = 0; j < 8; ++j) {
                acc[j]      += (float)a0[j] + (float)c0[j];
                acc[8 + j]  += (float)a1[j] + (float)c1[j];
                acc[16 + j] += (float)a2[j] + (float)c2[j];
                acc[24 + j] += (float)a3[j] + (float)c3[j];
            }
        }
        if (e < d) {
            int u = elist[b + e];
            if ((unsigned)u >= (unsigned)MN) u = 0;
            const __bf16* nb = H + (size_t)u * 256 + tc * 32;
            bf16x8 n0 = *(const bf16x8*)(nb + 0);
            bf16x8 n1 = *(const bf16x8*)(nb + 8);
            bf16x8 n2 = *(const bf16x8*)(nb + 16);
            bf16x8 n3 = *(const bf16x8*)(nb + 24);
#pragma unroll
            for (int j = 0; j < 8; ++j) {
                acc[j]      += (float)n0[j];
                acc[8 + j]  += (float)n1[j];
                acc[16 + j] += (float)n2[j];
                acc[24 + j] += (float)n3[j];
            }
        }
#pragma unroll
        for (int q = 0; q < 4; ++q) {
            int c = tc * 4 + q;      // bf16x8-chunk index 0..31
            bf16x8 o;
#pragma unroll
            for (int j = 0; j < 8; ++j) o[j] = (__bf16)acc[q * 8 + j];
            *(bf16x8*)(lA + r * 256 + ((c ^ (r & 7)) << 3)) = o;
        }
    }
}

// ---------------- fused GIN layer: Y = relu( relu((H+agg)@Wa+ba) @ Wb + bb ) ----------------
// r3/r9-proven config: 128-row tile, 8 waves, ci=2, 2 blocks/CU. ~113us/layer floor.
// do_pool: last layer skips the Y write and segment-sums the tile into POOL (batch sorted).
__global__ __launch_bounds__(512, 4) void k_agg_mlp(
    const __bf16* __restrict__ H, const int* __restrict__ offs, const int* __restrict__ deg,
    const int* __restrict__ elist,
    const __bf16* __restrict__ WaT, const void* __restrict__ ba,
    const __bf16* __restrict__ WbT, const void* __restrict__ bb,
    __bf16* __restrict__ Y, const int* __restrict__ batch,
    float* __restrict__ pool, float* __restrict__ cntf, int do_pool,
    int M_, const int* __restrict__ flags) {
    __shared__ __align__(16) __bf16 lA[128 * 256];
    __shared__ int sbatch[128];
    int t = threadIdx.x;
    int f32 = flags[0];
    int bm = blockIdx.x * 128;
    int w = t >> 6, lane = t & 63, lm = lane & 15, lq = lane >> 4;
    int n0 = w * 32;

    stage128_agg512(H, lA, offs, deg, elist, bm, t, M_);
    if (do_pool && t < 128) {
        int gm = bm + t;
        sbatch[t] = (gm < M_) ? loadI(batch, gm, flags[2]) : -1;
    }
    __syncthreads();

    {
        f32x4 acc[2][8] = {};
        gemm_core<2, 8>(lA, WaT, n0, lm, lq, acc);
        __syncthreads();   // all lA reads done; safe to overwrite with mid
        epi_to_lds<2, 8>(lA, acc, ba, n0, lm, lq, f32);
    }
    __syncthreads();

    f32x4 acc2[2][8] = {};
    gemm_core<2, 8>(lA, WbT, n0, lm, lq, acc2);
    __syncthreads();       // all lA reads done; safe to overwrite with result
    epi_to_lds<2, 8>(lA, acc2, bb, n0, lm, lq, f32);
    __syncthreads();

    if (!do_pool) {
        lds_to_global<16>(lA, Y, bm, w, lane, M_);
    } else {
        // segment mean-pool straight from LDS: thread = (col, row-half)
        int c = t & 255;
        int h2 = t >> 8;
        int g = -1;
        float acc = 0.f, run = 0.f;
        int rbeg = h2 * 64;
        for (int r = rbeg; r < rbeg + 64; ++r) {
            int bg = sbatch[r];
            if (bg < 0) break;   // past M_ (batch sorted)
            if ((unsigned)bg >= (unsigned)NG) bg = 0;
            float v = (float)lA[r * 256 + (((c >> 3) ^ (r & 7)) << 3) + (c & 7)];
            if (bg != g) {
                if (g >= 0) {
                    atomicAdd(&pool[(size_t)g * 256 + c], acc);
                    if (c == 0) atomicAdd(&cntf[g], run);
                }
                g = bg; acc = 0.f; run = 0.f;
            }
            acc += v; run += 1.f;
        }
        if (g >= 0) {
            atomicAdd(&pool[(size_t)g * 256 + c], acc);
            if (c == 0) atomicAdd(&cntf[g], run);
        }
    }
}

// ---------------- layer-1 GEMM: staging computes 7->256 linear from AGG7 ----------------
// 512 threads: staging at 4 threads/row (chain 896 -> 448 FMAs); 8-wave ci=2 GEMM path.
__global__ __launch_bounds__(512, 4) void k_gemm1(
    const float* __restrict__ agg7, const void* __restrict__ W1a, const void* __restrict__ b1a,
    const __bf16* __restrict__ WT, const void* __restrict__ bias,
    __bf16* __restrict__ Y, int M_, const int* __restrict__ flags) {
    __shared__ __align__(16) __bf16 lA[128 * 256];
    __shared__ float sW[7 * 256];
    __shared__ float sB[256];
    int t = threadIdx.x;
    int f32 = flags[0];
    int bm = blockIdx.x * 128;
    int w = t >> 6, lane = t & 63, lm = lane & 15, lq = lane >> 4;
    int n0 = w * 32;

    if (t < 256) sB[t] = loadF(b1a, t, f32);
    for (int i = t; i < 7 * 256; i += 512) sW[i] = loadF(W1a, i, f32);
    __syncthreads();

    {
        int r = t >> 2;                  // 4 threads/row over 128 rows
        int gr = bm + r;
        if (gr >= M_) gr = M_ - 1;
        float a[7];
#pragma unroll
        for (int k = 0; k < 7; ++k) a[k] = agg7[(size_t)gr * 8 + k];
        int c0 = (t & 3) * 64;
#pragma unroll
        for (int s8 = 0; s8 < 8; ++s8) {
            bf16x8 o;
#pragma unroll
            for (int j = 0; j < 8; ++j) {
                int cc = c0 + s8 * 8 + j;
                float v = sB[cc];
#pragma unroll
                for (int k = 0; k < 7; ++k) v = fmaf(a[k], sW[k * 256 + cc], v);
                o[j] = (__bf16)fmaxf(v, 0.f);
            }
            int ch = (c0 >> 3) + s8;
            *(bf16x8*)(lA + r * 256 + ((ch ^ (r & 7)) << 3)) = o;
        }
    }
    __syncthreads();

    f32x4 acc[2][8] = {};
    gemm_core<2, 8>(lA, WT, n0, lm, lq, acc);
    __syncthreads();
    epi_to_lds<2, 8>(lA, acc, bias, n0, lm, lq, f32);
    __syncthreads();
    lds_to_global<16>(lA, Y, bm, w, lane, M_);
}

// ---------------- head, split-K, 4 graphs/block: out[g] = relu(mean@Wh1+bh1)@Wh2+bh2 ----
// Each Wh1 element loaded once, FMA'd for FOUR graphs -> Wh1 L2 traffic 786/4 = 196 MB
// (r16's 2-graph variant measured -13us; same mechanism). 1500 blocks (~6/CU) keeps TLP
// well above the r5 failure point (750 blocks + 128KB LDS). Split-K chain stays 64.
// Output: 12 (graph,col) wave-reductions, round-robin over 8 waves.
__global__ __launch_bounds__(512) void k_head(
    const float* __restrict__ pool, const float* __restrict__ cnt,
    const void* __restrict__ Wh1, const void* __restrict__ bh1,
    const void* __restrict__ Wh2, const void* __restrict__ bh2,
    void* __restrict__ outv, const int* __restrict__ flags) {
    int g0 = blockIdx.x * 4, t = threadIdx.x;   // 512 threads, 4 graphs
    int f32 = flags[0];
    __shared__ float p[4][256];
    __shared__ float hidp[4][4][128];
    __shared__ float hid[4][128];
    for (int i = t; i < 4 * 256; i += 512) {
        int gl = i >> 8, k = i & 255;
        float inv = 1.0f / fmaxf(cnt[g0 + gl], 1.0f);
        p[gl][k] = pool[(size_t)(g0 + gl) * 256 + k] * inv;
    }
    __syncthreads();
    {
        int n = t & 127, kh = t >> 7;           // kh in 0..3: K-chunk of 64
        int kb = kh * 64;
        float s0 = 0.f, s1 = 0.f, s2 = 0.f, s3 = 0.f;
#pragma unroll 8
        for (int k = 0; k < 64; ++k) {
            float wv = loadF(Wh1, (size_t)(kb + k) * 128 + n, f32);
            s0 = fmaf(p[0][kb + k], wv, s0);
            s1 = fmaf(p[1][kb + k], wv, s1);
            s2 = fmaf(p[2][kb + k], wv, s2);
            s3 = fmaf(p[3][kb + k], wv, s3);
        }
        hidp[0][kh][n] = s0;
        hidp[1][kh][n] = s1;
        hidp[2][kh][n] = s2;
        hidp[3][kh][n] = s3;
    }
    __syncthreads();
    {
        int gl = t >> 7, n = t & 127;           // 512 threads cover 4x128
        hid[gl][n] = fmaxf(hidp[gl][0][n] + hidp[gl][1][n] + hidp[gl][2][n] + hidp[gl][3][n]
                           + loadF(bh1, n, f32), 0.f);
    }
    __syncthreads();
    {
        int wid = t >> 6, lane = t & 63;        // 8 waves handle 12 (graph,col) pairs
        for (int pair = wid; pair < 12; pair += 8) {
            int gl = pair / 3, n3 = pair % 3;
            float o = hid[gl][lane] * loadF(Wh2, (size_t)lane * 3 + n3, f32);
            o = fmaf(hid[gl][lane + 64], loadF(Wh2, (size_t)(lane + 64) * 3 + n3, f32), o);
#pragma unroll
            for (int off = 32; off > 0; off >>= 1) o += __shfl_down(o, off, 64);
            if (lane == 0) {
                o += loadF(bh2, n3, f32);
                int g = g0 + gl;
                if (f32) ((float*)outv)[(size_t)g * 3 + n3] = o;
                else     ((__bf16*)outv)[(size_t)g * 3 + n3] = (__bf16)o;
            }
        }
    }
}

// ---------------- launch ----------------
extern "C" void kernel_launch(void* const* d_in, const int* in_sizes, int n_in,
                              void* d_out, int out_size, void* d_ws, size_t ws_size,
                              hipStream_t stream) {
    const void* x     = d_in[0];
    const int*  ei    = (const int*)d_in[1];
    const int*  batch = (const int*)d_in[2];
    const void *W[4][2], *b[4][2];
    for (int l = 0; l < 4; ++l) {
        W[l][0] = d_in[3 + 4 * l];
        b[l][0] = d_in[4 + 4 * l];
        W[l][1] = d_in[5 + 4 * l];
        b[l][1] = d_in[6 + 4 * l];
    }
    const void* Wh1 = d_in[19];
    const void* bh1 = d_in[20];
    const void* Wh2 = d_in[21];
    const void* bh2 = d_in[22];

    char* p = (char*)d_ws;
    auto alloc = [&](size_t bytes) -> char* {
        char* r = p;
        p += (bytes + 255) & ~(size_t)255;
        return r;
    };
    __bf16* B1    = (__bf16*)alloc((size_t)MN * 256 * 2);   // 76.8 MB
    __bf16* B2    = (__bf16*)alloc((size_t)MN * 256 * 2);   // 76.8 MB
    __bf16* WT    = (__bf16*)alloc((size_t)7 * 256 * 256 * 2);
    float*  AGG7  = (float*)alloc((size_t)MN * 8 * 4);      // 4.8 MB
    int*    offs  = (int*)alloc((size_t)MN * 4);
    int*    cnt   = (int*)alloc((size_t)MN * 4);
    int*    elist = (int*)alloc((size_t)NEDGE * 4);
    int*    bsum  = (int*)alloc((size_t)NSCAN * 4);
    int*    bbase = (int*)alloc((size_t)NSCAN * 4);
    float*  POOL  = (float*)alloc((size_t)NG * 256 * 4);    // CNTF contiguous after
    float*  CNTF  = (float*)alloc((size_t)NG * 4);
    int*    flags = (int*)alloc(64);

    // ---- dtype probe ----
    k_probe<<<1, 256, 0, stream>>>(W[0][0], ei, batch, flags);

    // ---- transposed bf16 weights [n][k]: W1b, W2a, W2b, W3a, W3b, W4a, W4b ----
    k_cvtWT<<<7 * 256, 256, 0, stream>>>(W[0][1], W[1][0], W[1][1], W[2][0], W[2][1],
                                         W[3][0], W[3][1], WT, flags);

    // ---- CSR build (by dst) ----
    hipMemsetAsync(cnt, 0, (size_t)MN * 4, stream);
    k_deg<<<(NEDGE + 255) / 256, 256, 0, stream>>>(ei, cnt, NEDGE, flags);
    k_blksum<<<NSCAN, 256, 0, stream>>>(cnt, bsum, MN);
    k_scanb<<<1, 1024, 0, stream>>>(bsum, bbase, NSCAN);
    k_blkscan<<<NSCAN, 256, 0, stream>>>(cnt, bbase, offs, MN);
    hipMemsetAsync(cnt, 0, (size_t)MN * 4, stream);   // cursor
    k_fill<<<(NEDGE + 255) / 256, 256, 0, stream>>>(ei, offs, cnt, elist, NEDGE, flags);
    // after k_fill, cnt[v] == degree(v)

    // ---- zero pool accumulators (POOL + CNTF contiguous) ----
    hipMemsetAsync(POOL, 0, (size_t)NG * 256 * 4 + (size_t)NG * 4, stream);

    int gblocks = (MN + 127) / 128;

    // ---- layer 1: gather-7 + (lin1 fused into gemm1 staging) ----
    k_l1lite<<<(MN + 31) / 32, 256, 0, stream>>>(x, offs, cnt, elist, AGG7, flags, MN);
    k_gemm1<<<gblocks, 512, 0, stream>>>(AGG7, W[0][0], b[0][0], WT /*W1b^T*/, b[0][1],
                                         B1, MN, flags);

    // ---- layers 2..4: fused agg+MLP, ping-pong B1/B2; last layer pools in-epilogue ----
    __bf16* bin = B1;
    __bf16* bout = B2;
    for (int l = 1; l < 4; ++l) {
        const __bf16* WaT = WT + (size_t)(1 + 2 * (l - 1)) * 65536;
        const __bf16* WbT = WT + (size_t)(2 + 2 * (l - 1)) * 65536;
        int dp = (l == 3) ? 1 : 0;
        k_agg_mlp<<<gblocks, 512, 0, stream>>>(bin, offs, cnt, elist,
                                               WaT, b[l][0], WbT, b[l][1], bout,
                                               batch, POOL, CNTF, dp, MN, flags);
        __bf16* tmp = bin; bin = bout; bout = tmp;
    }

    // ---- split-K head, 4 graphs/block ----
    k_head<<<NG / 4, 512, 0, stream>>>(POOL, CNTF, Wh1, bh1, Wh2, bh2, d_out, flags);
}